// Round 5
// baseline (88.249 us; speedup 1.0000x reference)
//
#include <hip/hip_runtime.h>

// SelfAttention (lambda attention) on MI355X.
// B=8, C=256, H=W=32, n=1024, DK=64, HEADS=4, DQ=256, DV=64. SF = 64^-0.25
#define SFC 0.35355339059327373f

typedef __attribute__((ext_vector_type(8))) short short8;
typedef __attribute__((ext_vector_type(16))) float f32x16;
typedef unsigned short ushort_t;

__device__ __forceinline__ float4 ld4(const float* p) { return *reinterpret_cast<const float4*>(p); }
__device__ __forceinline__ void st4(float* p, float4 v) { *reinterpret_cast<float4*>(p) = v; }

union F4 { float4 v; float f[4]; };
union S8 { short8 v; ushort_t u[8]; };

__device__ __forceinline__ ushort_t bfb(float f) {
  union { float f; unsigned u; } a; a.f = f;
  unsigned r = a.u + 0x7FFFu + ((a.u >> 16) & 1u);   // RNE f32->bf16
  return (ushort_t)(r >> 16);
}

__device__ __forceinline__ void gl16(const void* g, void* l) {
  __builtin_amdgcn_global_load_lds(
      (const __attribute__((address_space(1))) unsigned int*)g,
      (__attribute__((address_space(3))) unsigned int*)l, 16, 0, 0);
}

// ---------------------------------------------------------------------------
// K0: prep. blocks 0..62: rpe -> RPEB bf16 [di][64 dj][72] (9216B slices)
//           blocks 63..110: Wq/Wk/Wv -> WB bf16 [384][256]
//           blocks 111..1134: x -> XBT bf16 [b*1024+n][256 c]
// block 0 also zeroes SUM/SUMSQ.
// ---------------------------------------------------------------------------
__global__ __launch_bounds__(256) void k_prep(
    const float* __restrict__ rpe, const float* __restrict__ wq,
    const float* __restrict__ wk, const float* __restrict__ wv,
    const float* __restrict__ x, ushort_t* __restrict__ RPEB,
    ushort_t* __restrict__ WB, ushort_t* __restrict__ XBT,
    float* __restrict__ SUM, float* __restrict__ SUMSQ)
{
  const int bx = blockIdx.x, t = threadIdx.x;
  if (bx < 63) {
    const int di = bx;
    if (bx == 0) {
      for (int i = t; i < 320; i += 256) { SUM[i] = 0.f; SUMSQ[i] = 0.f; }
    }
#pragma unroll
    for (int i = 0; i < 2; ++i) {
      const int c = t + i * 256;
      if (c < 504) {
        const int dj = c >> 3, k8 = (c & 7) * 8;
        const float* s = rpe + (size_t)di * 4032 + dj * 64 + k8;
        float4 a = ld4(s), b = ld4(s + 4);
        S8 o;
        o.u[0] = bfb(a.x); o.u[1] = bfb(a.y); o.u[2] = bfb(a.z); o.u[3] = bfb(a.w);
        o.u[4] = bfb(b.x); o.u[5] = bfb(b.y); o.u[6] = bfb(b.z); o.u[7] = bfb(b.w);
        *(short8*)(RPEB + (size_t)di * 4608 + dj * 72 + k8) = o.v;
      }
    }
  } else if (bx < 111) {
    const int cc = (bx - 63) * 256 + t;        // 0..12287
    const int o = cc >> 5, k8 = (cc & 31) * 8;
    const float* src = (o < 256) ? (wq + o * 256)
                      : (o < 320) ? (wk + (o - 256) * 256)
                                  : (wv + (o - 320) * 256);
    float4 a = ld4(src + k8), b = ld4(src + k8 + 4);
    S8 s;
    s.u[0] = bfb(a.x); s.u[1] = bfb(a.y); s.u[2] = bfb(a.z); s.u[3] = bfb(a.w);
    s.u[4] = bfb(b.x); s.u[5] = bfb(b.y); s.u[6] = bfb(b.z); s.u[7] = bfb(b.w);
    *(short8*)(WB + (size_t)o * 256 + k8) = s.v;
  } else {
    const int id = (bx - 111) * 256 + t;       // 0..262143
    const int ng = id & 8191, c8 = id >> 13;   // n global, c chunk
    const int bb = ng >> 10, nn = ng & 1023;
    const float* src = x + (size_t)bb * 262144 + (size_t)(c8 * 8) * 1024 + nn;
    S8 s;
#pragma unroll
    for (int j = 0; j < 8; ++j) s.u[j] = bfb(src[(size_t)j * 1024]);
    *(short8*)(XBT + (size_t)ng * 256 + c8 * 8) = s.v;
  }
}

// ---------------------------------------------------------------------------
// K1: projection GEMM via MFMA: P[o][col] = sum_c WB[o][c] * XBT[col][c].
// bm==5 (V rows) also emits VB bf16 slices [b][i2][v][40].
// bm<5 (q/k rows) also accumulates per-channel Sum/SumSq via shfl+atomicAdd.
// ---------------------------------------------------------------------------
__global__ __launch_bounds__(256) void k_projm(
    const ushort_t* __restrict__ WB, const ushort_t* __restrict__ XBT,
    float* __restrict__ P, ushort_t* __restrict__ VB,
    float* __restrict__ SUM, float* __restrict__ SUMSQ)
{
  __shared__ ushort_t At[64 * 72];
  __shared__ ushort_t Bt[128 * 72];
  const int t = threadIdx.x;
  const int bm = blockIdx.x, bn = blockIdx.y;
  const int o0 = bm * 64, col0 = bn * 128;
  const int w = t >> 6, l = t & 63, ln = l & 31, hi = l >> 5;
  const int wm = w & 1, wn = w >> 1;

  f32x16 acc0, acc1;
#pragma unroll
  for (int i = 0; i < 16; ++i) { acc0[i] = 0.f; acc1[i] = 0.f; }

  for (int k0 = 0; k0 < 256; k0 += 64) {
    __syncthreads();
#pragma unroll
    for (int i = 0; i < 2; ++i) {
      const int c = t + i * 256, row = c >> 3, k8 = (c & 7) * 8;
      *(short8*)(At + row * 72 + k8) =
          *(const short8*)(WB + (size_t)(o0 + row) * 256 + k0 + k8);
    }
#pragma unroll
    for (int i = 0; i < 4; ++i) {
      const int c = t + i * 256, row = c >> 3, k8 = (c & 7) * 8;
      *(short8*)(Bt + row * 72 + k8) =
          *(const short8*)(XBT + (size_t)(col0 + row) * 256 + k0 + k8);
    }
    __syncthreads();
    const ushort_t* ka  = At + (wm * 32 + ln) * 72 + hi * 8;
    const ushort_t* kb0 = Bt + (wn * 64 + ln) * 72 + hi * 8;
    const ushort_t* kb1 = Bt + (wn * 64 + 32 + ln) * 72 + hi * 8;
#pragma unroll
    for (int kc = 0; kc < 4; ++kc) {
      short8 a = *(const short8*)(ka + kc * 16);
      acc0 = __builtin_amdgcn_mfma_f32_32x32x16_bf16(a, *(const short8*)(kb0 + kc * 16), acc0, 0, 0, 0);
      acc1 = __builtin_amdgcn_mfma_f32_32x32x16_bf16(a, *(const short8*)(kb1 + kc * 16), acc1, 0, 0, 0);
    }
  }

#pragma unroll
  for (int r = 0; r < 16; ++r) {
    const int o = o0 + wm * 32 + (r & 3) + 8 * (r >> 2) + 4 * hi;
    float* dst = P + (size_t)o * 8192 + col0 + wn * 64 + ln;
    dst[0]  = acc0[r];
    dst[32] = acc1[r];
  }
  if (bm == 5) {
    const int b2 = bn >> 3;
#pragma unroll
    for (int r = 0; r < 16; ++r) {
      const int v = wm * 32 + (r & 3) + 8 * (r >> 2) + 4 * hi;
      const int i20 = (bn & 7) * 4 + wn * 2;
      VB[(size_t)(b2 * 32 + i20) * 2560 + v * 40 + ln]     = bfb(acc0[r]);
      VB[(size_t)(b2 * 32 + i20 + 1) * 2560 + v * 40 + ln] = bfb(acc1[r]);
    }
  } else {
    // BN stats partials: per-row sum over this wave's 64 cols, then atomic
#pragma unroll
    for (int r = 0; r < 16; ++r) {
      float s1 = acc0[r] + acc1[r];
      float s2 = acc0[r] * acc0[r] + acc1[r] * acc1[r];
#pragma unroll
      for (int off = 1; off < 32; off <<= 1) {
        s1 += __shfl_xor(s1, off, 64);
        s2 += __shfl_xor(s2, off, 64);
      }
      if (ln == 0) {
        const int o = o0 + wm * 32 + (r & 3) + 8 * (r >> 2) + 4 * hi;
        atomicAdd(&SUM[o], s1);
        atomicAdd(&SUMSQ[o], s2);
      }
    }
  }
}

// ---------------------------------------------------------------------------
// K2: softmax over n per (b, k-channel); BN scale/shift finalized inline from
// SUM/SUMSQ. Writes KSB bf16 [b][kc][1024].
// ---------------------------------------------------------------------------
__global__ __launch_bounds__(256) void k_softmax(
    const float* __restrict__ P, const float* __restrict__ SUM,
    const float* __restrict__ SUMSQ, const float* __restrict__ gk,
    const float* __restrict__ bk, ushort_t* __restrict__ KSB)
{
  const int b = blockIdx.x >> 6, kc = blockIdx.x & 63;
  const int ch = 256 + kc;
  const float mu = SUM[ch] * (1.0f / 8192.0f);
  const float var = SUMSQ[ch] * (1.0f / 8192.0f) - mu * mu;
  const float sc0 = rsqrtf(var + 1e-5f) * gk[kc] * SFC;
  const float sc = sc0, sh = bk[kc] * SFC - mu * sc0;

  const float4* row = (const float4*)(P + (size_t)ch * 8192 + b * 1024);
  float4 v = row[threadIdx.x];
  float y0 = v.x * sc + sh, y1 = v.y * sc + sh;
  float y2 = v.z * sc + sh, y3 = v.w * sc + sh;
  float m = fmaxf(fmaxf(y0, y1), fmaxf(y2, y3));
#pragma unroll
  for (int off = 32; off; off >>= 1) m = fmaxf(m, __shfl_xor(m, off, 64));
  __shared__ float red[8];
  const int w = threadIdx.x >> 6, lane = threadIdx.x & 63;
  if (lane == 0) red[w] = m;
  __syncthreads();
  m = fmaxf(fmaxf(red[0], red[1]), fmaxf(red[2], red[3]));
  const float e0 = __expf(y0 - m), e1 = __expf(y1 - m);
  const float e2 = __expf(y2 - m), e3 = __expf(y3 - m);
  float su = e0 + e1 + e2 + e3;
#pragma unroll
  for (int off = 32; off; off >>= 1) su += __shfl_xor(su, off, 64);
  if (lane == 0) red[4 + w] = su;
  __syncthreads();
  const float inv = 1.0f / (red[4] + red[5] + red[6] + red[7]);
  ushort4 u;
  u.x = bfb(e0 * inv); u.y = bfb(e1 * inv);
  u.z = bfb(e2 * inv); u.w = bfb(e3 * inv);
  ((ushort4*)(KSB + (size_t)(b * 64 + kc) * 1024))[threadIdx.x] = u;
}

// ---------------------------------------------------------------------------
// K3: content context via MFMA: ctx[k][v] = sum_n ks[k][n]*v[v][n] per b.
// Writes CTXB bf16 [b][v][72 k-pad] directly. Grid 8, 256 threads (4 waves:
// wave w -> kc-tile a=w&1, vc-tile bt=w>>1).
// ---------------------------------------------------------------------------
__global__ __launch_bounds__(256) void k_ctxm(
    const ushort_t* __restrict__ KSB, const ushort_t* __restrict__ VB,
    ushort_t* __restrict__ CTXB)
{
  __shared__ ushort_t KT[2][64 * 72];
  __shared__ ushort_t VT[2][64 * 72];
  const int b = blockIdx.x, t = threadIdx.x;
  const int w = t >> 6, l = t & 63, ln = l & 31, hi = l >> 5;
  const int a = w & 1, bt = w >> 1;

  auto stageC = [&](int ch, int buf) {
    const int n0 = ch * 64;
#pragma unroll
    for (int it = 0; it < 2; ++it) {
      const int idx = t + it * 256;
      const int row = idx >> 3, seg = idx & 7;
      *(short8*)(&KT[buf][row * 72 + seg * 8]) =
          *(const short8*)(KSB + (size_t)(b * 64 + row) * 1024 + n0 + seg * 8);
      const int i2h = (n0 >> 5) + (seg >> 2);
      *(short8*)(&VT[buf][row * 72 + seg * 8]) =
          *(const short8*)(VB + (size_t)(b * 32 + i2h) * 2560 + row * 40 + (seg & 3) * 8);
    }
  };

  f32x16 acc;
#pragma unroll
  for (int i = 0; i < 16; ++i) acc[i] = 0.f;

  stageC(0, 0);
  for (int ch = 0; ch < 16; ++ch) {
    const int cur = ch & 1;
    __syncthreads();
    if (ch + 1 < 16) stageC(ch + 1, cur ^ 1);
    const ushort_t* ka = &KT[cur][(a * 32 + ln) * 72 + hi * 8];
    const ushort_t* kb = &VT[cur][(bt * 32 + ln) * 72 + hi * 8];
#pragma unroll
    for (int kc = 0; kc < 4; ++kc)
      acc = __builtin_amdgcn_mfma_f32_32x32x16_bf16(
          *(const short8*)(ka + kc * 16), *(const short8*)(kb + kc * 16), acc, 0, 0, 0);
  }
#pragma unroll
  for (int r = 0; r < 16; ++r) {
    const int kc = a * 32 + (r & 3) + 8 * (r >> 2) + 4 * hi;
    CTXB[(size_t)b * 4608 + (bt * 32 + ln) * 72 + kc] = bfb(acc[r]);
  }
}

// ---------------------------------------------------------------------------
// K5: positional lambda, block = (b, i1), grid 256, 8 waves (head m, group g).
// 4-buffer LDS pipeline, 2-deep gl16 prefetch, counted vmcnt + raw barrier,
// setprio around MFMA clusters. BN scale for q finalized inline.
// ---------------------------------------------------------------------------
extern __shared__ char ldsc[];

__global__ __launch_bounds__(512) void k_pos(
    const float* __restrict__ P, const ushort_t* __restrict__ RPEB,
    const ushort_t* __restrict__ VB, const float* __restrict__ SUM,
    const float* __restrict__ SUMSQ, const float* __restrict__ gq,
    const float* __restrict__ bq, const ushort_t* __restrict__ CTXB,
    float* __restrict__ out)
{
  // layout: [0,33792) qst f32 [256][33] (bufs 3 overlay here; out_l at end)
  //         [33792, 33792+3*28672) bufs 0..2: per buf {g0: R 9216 + V 5120,
  //                                                    g1: R 9216 + V 5120}
  //         [119808, 140288) SlB: 8 waves x 1280 ushorts
  float* qst = (float*)ldsc;
  ushort_t* SlB = (ushort_t*)(ldsc + 119808);

  const int t = threadIdx.x;
  const int b = blockIdx.x >> 5, i1 = blockIdx.x & 31;
  const int w = t >> 6, l = t & 63, ln = l & 31, hi = l >> 5;
  const int m = w & 3, g = w >> 2;

  auto bufp = [&](int buf, int gg) -> char* {
    char* base = (buf < 3) ? (ldsc + 33792 + buf * 28672) : ldsc;
    return base + gg * 14336;
  };

  // async stage of slice i2 into buffer buf: uniform 4 gl16 per wave
  auto stage = [&](int i2, int buf) {
    const char* rs = (const char*)RPEB + (size_t)(i2 - i1 + 31) * 9216;
    const char* vs = (const char*)VB + (size_t)(b * 32 + i2) * 5120;
    char* bb_ = bufp(buf, g);
    char* rd = bb_;
    char* vd = bb_ + 9216;
    const int off = l * 16;
#pragma unroll
    for (int j = 0; j < 4; ++j) {
      const int c = m * 4 + j;
      if (c < 9)       gl16(rs + c * 1024 + off, rd + c * 1024 + off);
      else if (c < 14) gl16(vs + (c - 9) * 1024 + off, vd + (c - 9) * 1024 + off);
      else             gl16(rs + (c - 14) * 1024 + off, rd + (c - 14) * 1024 + off);
    }
  };

  const int i2base = g * 16;
  stage(i2base + 0, 0);
  stage(i2base + 1, 1);

  // ---- stage scaled q [256 ch][32 j1] f32 (BN finalize inline) ----
  {
    const int j1 = t & 31, c0 = (t >> 5) * 16;
    const float* src = P + (size_t)b * 1024 + i1 * 32 + j1;
#pragma unroll
    for (int i = 0; i < 16; ++i) {
      const int ch = c0 + i;
      const float mu = SUM[ch] * (1.0f / 8192.0f);
      const float var = SUMSQ[ch] * (1.0f / 8192.0f) - mu * mu;
      const float sc = rsqrtf(var + 1e-5f) * gq[ch] * SFC;
      const float sh = bq[ch] * SFC - mu * sc;
      qst[ch * 33 + j1] = src[(size_t)ch * 8192] * sc + sh;
    }
  }
  __syncthreads();

  // ---- q A-fragments for head m ----
  short8 qf[4];
#pragma unroll
  for (int kc = 0; kc < 4; ++kc) {
    S8 s;
#pragma unroll
    for (int i = 0; i < 8; ++i)
      s.u[i] = bfb(qst[(m * 64 + kc * 16 + hi * 8 + i) * 33 + ln]);
    qf[kc] = s.v;
  }
  __syncthreads();   // qst reads done: buf3 (overlay) may now be written

  f32x16 sv0, sv1;
#pragma unroll
  for (int i = 0; i < 16; ++i) { sv0[i] = 0.f; sv1[i] = 0.f; }

  ushort_t* sm = SlB + w * 1280;             // private S tile [32 j1][40]

  for (int s = 0; s < 16; ++s) {
    const int cur = s & 3;
    if (s + 2 < 16) stage(i2base + s + 2, (s + 2) & 3);
    if (s < 14)       asm volatile("s_waitcnt vmcnt(8)" ::: "memory");
    else if (s == 14) asm volatile("s_waitcnt vmcnt(4)" ::: "memory");
    else              asm volatile("s_waitcnt vmcnt(0)" ::: "memory");
    __builtin_amdgcn_sched_barrier(0);
    __builtin_amdgcn_s_barrier();

    const char* bb_ = bufp(cur, g);
    // T-GEMM: T[j1, dj] = sum_k q[k,j1]*rpe[di][dj][k]
    f32x16 t0, t1;
#pragma unroll
    for (int i = 0; i < 16; ++i) { t0[i] = 0.f; t1[i] = 0.f; }
    {
      const ushort_t* rb = (const ushort_t*)bb_;
      const ushort_t* r0 = rb + ln * 72 + hi * 8;
      const ushort_t* r1 = rb + (32 + ln) * 72 + hi * 8;
      __builtin_amdgcn_s_setprio(1);
#pragma unroll
      for (int kc = 0; kc < 4; ++kc) {
        t0 = __builtin_amdgcn_mfma_f32_32x32x16_bf16(qf[kc], *(const short8*)(r0 + kc * 16), t0, 0, 0, 0);
        t1 = __builtin_amdgcn_mfma_f32_32x32x16_bf16(qf[kc], *(const short8*)(r1 + kc * 16), t1, 0, 0, 0);
      }
      __builtin_amdgcn_s_setprio(0);
    }
    // shear into private Sl: S[j1][j2 = dj + j1 - 31]
#pragma unroll
    for (int r = 0; r < 16; ++r) {
      const int j1 = (r & 3) + 8 * (r >> 2) + 4 * hi;
      const int j2a = ln + j1 - 31;
      const int j2b = 32 + ln + j1 - 31;
      if ((unsigned)j2a < 32u) sm[j1 * 40 + j2a] = bfb(t0[r]);
      if ((unsigned)j2b < 32u) sm[j1 * 40 + j2b] = bfb(t1[r]);
    }
    // SV: out[j1, v] += sum_j2 S[j1,j2] * V[v,j2]
    {
      const ushort_t* sa = sm + ln * 40 + hi * 8;
      const ushort_t* vbp = (const ushort_t*)(bb_ + 9216);
      const ushort_t* v0 = vbp + ln * 40 + hi * 8;
      const ushort_t* v1 = vbp + (32 + ln) * 40 + hi * 8;
      short8 sA0 = *(const short8*)(sa);
      short8 sA1 = *(const short8*)(sa + 16);
      __builtin_amdgcn_s_setprio(1);
      sv0 = __builtin_amdgcn_mfma_f32_32x32x16_bf16(sA0, *(const short8*)(v0),      sv0, 0, 0, 0);
      sv0 = __builtin_amdgcn_mfma_f32_32x32x16_bf16(sA1, *(const short8*)(v0 + 16), sv0, 0, 0, 0);
      sv1 = __builtin_amdgcn_mfma_f32_32x32x16_bf16(sA0, *(const short8*)(v1),      sv1, 0, 0, 0);
      sv1 = __builtin_amdgcn_mfma_f32_32x32x16_bf16(sA1, *(const short8*)(v1 + 16), sv1, 0, 0, 0);
      __builtin_amdgcn_s_setprio(0);
    }
  }

  // ---- content epilogue: stage CTXB into buf0-g0 R area ----
  {
    char* cdst = bufp(0, 0);
    const char* cs = (const char*)CTXB + (size_t)b * 9216;
    if (w < 8) gl16(cs + w * 1024 + l * 16, cdst + w * 1024 + l * 16);
    if (w == 0) gl16(cs + 8192 + l * 16, cdst + 8192 + l * 16);
  }
  __syncthreads();     // full drain: ctx staged, all compute done

  float* out_l = qst;  // [256][33]
  if (g == 0) {
    const ushort_t* cb = (const ushort_t*)bufp(0, 0);
    const ushort_t* c0 = cb + ln * 72 + hi * 8;
    const ushort_t* c1 = cb + (32 + ln) * 72 + hi * 8;
#pragma unroll
    for (int kc = 0; kc < 4; ++kc) {
      sv0 = __builtin_amdgcn_mfma_f32_32x32x16_bf16(qf[kc], *(const short8*)(c0 + kc * 16), sv0, 0, 0, 0);
      sv1 = __builtin_amdgcn_mfma_f32_32x32x16_bf16(qf[kc], *(const short8*)(c1 + kc * 16), sv1, 0, 0, 0);
    }
  } else {
#pragma unroll
    for (int r = 0; r < 16; ++r) {
      const int j1 = (r & 3) + 8 * (r >> 2) + 4 * hi;
      out_l[(m * 64 + ln) * 33 + j1]      = sv0[r];
      out_l[(m * 64 + 32 + ln) * 33 + j1] = sv1[r];
    }
  }
  __syncthreads();
  if (g == 0) {
#pragma unroll
    for (int r = 0; r < 16; ++r) {
      const int j1 = (r & 3) + 8 * (r >> 2) + 4 * hi;
      out_l[(m * 64 + ln) * 33 + j1]      += sv0[r];
      out_l[(m * 64 + 32 + ln) * 33 + j1] += sv1[r];
    }
  }
  __syncthreads();
  {
    const int ch = t >> 1, jh = (t & 1) * 16;
    float* dst = out + (size_t)b * 262144 + (size_t)ch * 1024 + i1 * 32 + jh;
    const float* srow = out_l + ch * 33 + jh;
#pragma unroll
    for (int gg = 0; gg < 4; ++gg)
      st4(dst + gg * 4, make_float4(srow[gg * 4], srow[gg * 4 + 1],
                                    srow[gg * 4 + 2], srow[gg * 4 + 3]));
  }
}

// ---------------------------------------------------------------------------
extern "C" void kernel_launch(void* const* d_in, const int* in_sizes, int n_in,
                              void* d_out, int out_size, void* d_ws, size_t ws_size,
                              hipStream_t stream) {
  const float* x   = (const float*)d_in[0];
  const float* wq  = (const float*)d_in[1];
  const float* gq  = (const float*)d_in[2];
  const float* bq  = (const float*)d_in[3];
  const float* wk  = (const float*)d_in[4];
  const float* gk  = (const float*)d_in[5];
  const float* bk  = (const float*)d_in[6];
  const float* wv  = (const float*)d_in[7];
  const float* rpe = (const float*)d_in[8];
  float* out = (float*)d_out;
  char* W = (char*)d_ws;

  float* P        = (float*)W;                       // 12,582,912 B
  ushort_t* KSB   = (ushort_t*)(W + 12582912);       //  1,048,576
  float* SUM      = (float*)(W + 13631488);          //      1,280 (pad 2048)
  float* SUMSQ    = (float*)(W + 13633536);          //      1,280 (pad 2048)
  ushort_t* CTXB  = (ushort_t*)(W + 13635584);       //     73,728
  ushort_t* RPEB  = (ushort_t*)(W + 13709312);       //    580,608
  ushort_t* VB    = (ushort_t*)(W + 14289920);       //  1,310,720
  ushort_t* WB    = (ushort_t*)(W + 15600640);       //    196,608
  ushort_t* XBT   = (ushort_t*)(W + 15797248);       //  4,194,304

  k_prep<<<1135, 256, 0, stream>>>(rpe, wq, wk, wv, x, RPEB, WB, XBT, SUM, SUMSQ);
  k_projm<<<dim3(6, 64), 256, 0, stream>>>(WB, XBT, P, VB, SUM, SUMSQ);
  k_softmax<<<512, 256, 0, stream>>>(P, SUM, SUMSQ, gk, bk, KSB);
  k_ctxm<<<8, 256, 0, stream>>>(KSB, VB, CTXB);

  hipFuncSetAttribute((const void*)k_pos,
                      hipFuncAttributeMaxDynamicSharedMemorySize, 140288);
  k_pos<<<256, 512, 140288, stream>>>(P, RPEB, VB, SUM, SUMSQ, gq, bq, CTXB, out);
}

// Round 6
// 72.707 us; speedup vs baseline: 1.2138x; 1.2138x over previous
//
#include <hip/hip_runtime.h>

// SelfAttention (lambda attention) on MI355X.
// B=8, C=256, H=W=32, n=1024, DK=64, HEADS=4, DQ=256, DV=64. SF = 64^-0.25
#define SFC 0.35355339059327373f

typedef __attribute__((ext_vector_type(8))) short short8;
typedef __attribute__((ext_vector_type(16))) float f32x16;
typedef unsigned short ushort_t;

__device__ __forceinline__ float4 ld4(const float* p) { return *reinterpret_cast<const float4*>(p); }
__device__ __forceinline__ void st4(float* p, float4 v) { *reinterpret_cast<float4*>(p) = v; }

union F4 { float4 v; float f[4]; };
union S8 { short8 v; ushort_t u[8]; };

__device__ __forceinline__ ushort_t bfb(float f) {
  union { float f; unsigned u; } a; a.f = f;
  unsigned r = a.u + 0x7FFFu + ((a.u >> 16) & 1u);   // RNE f32->bf16
  return (ushort_t)(r >> 16);
}

__device__ __forceinline__ void gl16(const void* g, void* l) {
  __builtin_amdgcn_global_load_lds(
      (const __attribute__((address_space(1))) unsigned int*)g,
      (__attribute__((address_space(3))) unsigned int*)l, 16, 0, 0);
}

// ---------------------------------------------------------------------------
// K0: prep. blocks 0..62: rpe -> RPEB bf16 [di][64 dj][72] (9216B slices)
//           blocks 63..110: Wq/Wk/Wv -> WB bf16 [384][256]
//           blocks 111..1134: x -> XBT bf16 [b*1024+n][256 c]
// ---------------------------------------------------------------------------
__global__ __launch_bounds__(256) void k_prep(
    const float* __restrict__ rpe, const float* __restrict__ wq,
    const float* __restrict__ wk, const float* __restrict__ wv,
    const float* __restrict__ x, ushort_t* __restrict__ RPEB,
    ushort_t* __restrict__ WB, ushort_t* __restrict__ XBT)
{
  const int bx = blockIdx.x, t = threadIdx.x;
  if (bx < 63) {
    const int di = bx;
#pragma unroll
    for (int i = 0; i < 2; ++i) {
      const int c = t + i * 256;
      if (c < 504) {
        const int dj = c >> 3, k8 = (c & 7) * 8;
        const float* s = rpe + (size_t)di * 4032 + dj * 64 + k8;
        float4 a = ld4(s), b = ld4(s + 4);
        S8 o;
        o.u[0] = bfb(a.x); o.u[1] = bfb(a.y); o.u[2] = bfb(a.z); o.u[3] = bfb(a.w);
        o.u[4] = bfb(b.x); o.u[5] = bfb(b.y); o.u[6] = bfb(b.z); o.u[7] = bfb(b.w);
        *(short8*)(RPEB + (size_t)di * 4608 + dj * 72 + k8) = o.v;
      }
    }
  } else if (bx < 111) {
    const int cc = (bx - 63) * 256 + t;        // 0..12287
    const int o = cc >> 5, k8 = (cc & 31) * 8;
    const float* src = (o < 256) ? (wq + o * 256)
                      : (o < 320) ? (wk + (o - 256) * 256)
                                  : (wv + (o - 320) * 256);
    float4 a = ld4(src + k8), b = ld4(src + k8 + 4);
    S8 s;
    s.u[0] = bfb(a.x); s.u[1] = bfb(a.y); s.u[2] = bfb(a.z); s.u[3] = bfb(a.w);
    s.u[4] = bfb(b.x); s.u[5] = bfb(b.y); s.u[6] = bfb(b.z); s.u[7] = bfb(b.w);
    *(short8*)(WB + (size_t)o * 256 + k8) = s.v;
  } else {
    const int id = (bx - 111) * 256 + t;       // 0..262143
    const int ng = id & 8191, c8 = id >> 13;   // n global, c chunk
    const int bb = ng >> 10, nn = ng & 1023;
    const float* src = x + (size_t)bb * 262144 + (size_t)(c8 * 8) * 1024 + nn;
    S8 s;
#pragma unroll
    for (int j = 0; j < 8; ++j) s.u[j] = bfb(src[(size_t)j * 1024]);
    *(short8*)(XBT + (size_t)ng * 256 + c8 * 8) = s.v;
  }
}

// ---------------------------------------------------------------------------
// K1: projection GEMM via MFMA: P[o][col] = sum_c WB[o][c] * XBT[col][c].
// bm==5 (V rows) also emits VB bf16 slices [b][i2][v][40].
// bm<5 (q/k rows): per-wave column sums -> non-atomic partials
// PSUM/PSQ[o][128] at slot bn*2+wn.
// ---------------------------------------------------------------------------
__global__ __launch_bounds__(256) void k_projm(
    const ushort_t* __restrict__ WB, const ushort_t* __restrict__ XBT,
    float* __restrict__ P, ushort_t* __restrict__ VB,
    float* __restrict__ PSUM, float* __restrict__ PSQ)
{
  __shared__ ushort_t At[64 * 72];
  __shared__ ushort_t Bt[128 * 72];
  const int t = threadIdx.x;
  const int bm = blockIdx.x, bn = blockIdx.y;
  const int o0 = bm * 64, col0 = bn * 128;
  const int w = t >> 6, l = t & 63, ln = l & 31, hi = l >> 5;
  const int wm = w & 1, wn = w >> 1;

  f32x16 acc0, acc1;
#pragma unroll
  for (int i = 0; i < 16; ++i) { acc0[i] = 0.f; acc1[i] = 0.f; }

  for (int k0 = 0; k0 < 256; k0 += 64) {
    __syncthreads();
#pragma unroll
    for (int i = 0; i < 2; ++i) {
      const int c = t + i * 256, row = c >> 3, k8 = (c & 7) * 8;
      *(short8*)(At + row * 72 + k8) =
          *(const short8*)(WB + (size_t)(o0 + row) * 256 + k0 + k8);
    }
#pragma unroll
    for (int i = 0; i < 4; ++i) {
      const int c = t + i * 256, row = c >> 3, k8 = (c & 7) * 8;
      *(short8*)(Bt + row * 72 + k8) =
          *(const short8*)(XBT + (size_t)(col0 + row) * 256 + k0 + k8);
    }
    __syncthreads();
    const ushort_t* ka  = At + (wm * 32 + ln) * 72 + hi * 8;
    const ushort_t* kb0 = Bt + (wn * 64 + ln) * 72 + hi * 8;
    const ushort_t* kb1 = Bt + (wn * 64 + 32 + ln) * 72 + hi * 8;
#pragma unroll
    for (int kc = 0; kc < 4; ++kc) {
      short8 a = *(const short8*)(ka + kc * 16);
      acc0 = __builtin_amdgcn_mfma_f32_32x32x16_bf16(a, *(const short8*)(kb0 + kc * 16), acc0, 0, 0, 0);
      acc1 = __builtin_amdgcn_mfma_f32_32x32x16_bf16(a, *(const short8*)(kb1 + kc * 16), acc1, 0, 0, 0);
    }
  }

#pragma unroll
  for (int r = 0; r < 16; ++r) {
    const int o = o0 + wm * 32 + (r & 3) + 8 * (r >> 2) + 4 * hi;
    float* dst = P + (size_t)o * 8192 + col0 + wn * 64 + ln;
    dst[0]  = acc0[r];
    dst[32] = acc1[r];
  }
  if (bm == 5) {
    const int b2 = bn >> 3;
#pragma unroll
    for (int r = 0; r < 16; ++r) {
      const int v = wm * 32 + (r & 3) + 8 * (r >> 2) + 4 * hi;
      const int i20 = (bn & 7) * 4 + wn * 2;
      VB[(size_t)(b2 * 32 + i20) * 2560 + v * 40 + ln]     = bfb(acc0[r]);
      VB[(size_t)(b2 * 32 + i20 + 1) * 2560 + v * 40 + ln] = bfb(acc1[r]);
    }
  } else {
    // per-wave column sums (64 cols) -> non-atomic partial slot
#pragma unroll
    for (int r = 0; r < 16; ++r) {
      float s1 = acc0[r] + acc1[r];
      float s2 = acc0[r] * acc0[r] + acc1[r] * acc1[r];
#pragma unroll
      for (int off = 1; off < 32; off <<= 1) {
        s1 += __shfl_xor(s1, off, 64);
        s2 += __shfl_xor(s2, off, 64);
      }
      if (ln == 0) {
        const int o = o0 + wm * 32 + (r & 3) + 8 * (r >> 2) + 4 * hi;
        PSUM[o * 128 + bn * 2 + wn] = s1;
        PSQ [o * 128 + bn * 2 + wn] = s2;
      }
    }
  }
}

// ---------------------------------------------------------------------------
// K2: BN finalize: reduce 128 partials per channel -> SCALE/SHIFT.
// ---------------------------------------------------------------------------
__global__ __launch_bounds__(128) void k_bnfin(
    const float* __restrict__ PSUM, const float* __restrict__ PSQ,
    const float* __restrict__ gq, const float* __restrict__ bq,
    const float* __restrict__ gk, const float* __restrict__ bk,
    float* __restrict__ scale, float* __restrict__ shift)
{
  const int ch = blockIdx.x, t = threadIdx.x;
  float s1 = PSUM[ch * 128 + t];
  float s2 = PSQ[ch * 128 + t];
#pragma unroll
  for (int off = 1; off < 64; off <<= 1) {
    s1 += __shfl_xor(s1, off, 64);
    s2 += __shfl_xor(s2, off, 64);
  }
  __shared__ float red[4];
  if ((t & 63) == 0) { red[t >> 6] = s1; red[2 + (t >> 6)] = s2; }
  __syncthreads();
  if (t == 0) {
    s1 = red[0] + red[1];
    s2 = red[2] + red[3];
    const float mu = s1 * (1.0f / 8192.0f);
    const float var = s2 * (1.0f / 8192.0f) - mu * mu;
    const float rsig = rsqrtf(var + 1e-5f);
    float g, be;
    if (ch < 256) { g = gq[ch]; be = bq[ch]; }
    else          { g = gk[ch - 256]; be = bk[ch - 256]; }
    const float sc = rsig * g * SFC;
    scale[ch] = sc;
    shift[ch] = be * SFC - mu * sc;
  }
}

// ---------------------------------------------------------------------------
// K3: softmax over n per (b, k-channel). Writes KSB bf16 [b][kc][1024].
// ---------------------------------------------------------------------------
__global__ __launch_bounds__(256) void k_softmax(
    const float* __restrict__ P, const float* __restrict__ scale,
    const float* __restrict__ shift, ushort_t* __restrict__ KSB)
{
  const int b = blockIdx.x >> 6, kc = blockIdx.x & 63;
  const int ch = 256 + kc;
  const float sc = scale[ch], sh = shift[ch];
  const float4* row = (const float4*)(P + (size_t)ch * 8192 + b * 1024);
  float4 v = row[threadIdx.x];
  float y0 = v.x * sc + sh, y1 = v.y * sc + sh;
  float y2 = v.z * sc + sh, y3 = v.w * sc + sh;
  float m = fmaxf(fmaxf(y0, y1), fmaxf(y2, y3));
#pragma unroll
  for (int off = 32; off; off >>= 1) m = fmaxf(m, __shfl_xor(m, off, 64));
  __shared__ float red[8];
  const int w = threadIdx.x >> 6, lane = threadIdx.x & 63;
  if (lane == 0) red[w] = m;
  __syncthreads();
  m = fmaxf(fmaxf(red[0], red[1]), fmaxf(red[2], red[3]));
  const float e0 = __expf(y0 - m), e1 = __expf(y1 - m);
  const float e2 = __expf(y2 - m), e3 = __expf(y3 - m);
  float su = e0 + e1 + e2 + e3;
#pragma unroll
  for (int off = 32; off; off >>= 1) su += __shfl_xor(su, off, 64);
  if (lane == 0) red[4 + w] = su;
  __syncthreads();
  const float inv = 1.0f / (red[4] + red[5] + red[6] + red[7]);
  ushort4 u;
  u.x = bfb(e0 * inv); u.y = bfb(e1 * inv);
  u.z = bfb(e2 * inv); u.w = bfb(e3 * inv);
  ((ushort4*)(KSB + (size_t)(b * 64 + kc) * 1024))[threadIdx.x] = u;
}

// ---------------------------------------------------------------------------
// K4: content context via MFMA: ctx[k][v] = sum_n ks[k][n]*v[v][n] per b.
// Writes CTXB bf16 [b][v][72 k-pad]. Grid 8, 4 waves (kc-tile a, vc-tile bt).
// ---------------------------------------------------------------------------
__global__ __launch_bounds__(256) void k_ctxm(
    const ushort_t* __restrict__ KSB, const ushort_t* __restrict__ VB,
    ushort_t* __restrict__ CTXB)
{
  __shared__ ushort_t KT[2][64 * 72];
  __shared__ ushort_t VT[2][64 * 72];
  const int b = blockIdx.x, t = threadIdx.x;
  const int w = t >> 6, l = t & 63, ln = l & 31, hi = l >> 5;
  const int a = w & 1, bt = w >> 1;

  auto stageC = [&](int ch, int buf) {
    const int n0 = ch * 64;
#pragma unroll
    for (int it = 0; it < 2; ++it) {
      const int idx = t + it * 256;
      const int row = idx >> 3, seg = idx & 7;
      *(short8*)(&KT[buf][row * 72 + seg * 8]) =
          *(const short8*)(KSB + (size_t)(b * 64 + row) * 1024 + n0 + seg * 8);
      const int i2h = (n0 >> 5) + (seg >> 2);
      *(short8*)(&VT[buf][row * 72 + seg * 8]) =
          *(const short8*)(VB + (size_t)(b * 32 + i2h) * 2560 + row * 40 + (seg & 3) * 8);
    }
  };

  f32x16 acc;
#pragma unroll
  for (int i = 0; i < 16; ++i) acc[i] = 0.f;

  stageC(0, 0);
  for (int ch = 0; ch < 16; ++ch) {
    const int cur = ch & 1;
    __syncthreads();
    if (ch + 1 < 16) stageC(ch + 1, cur ^ 1);
    const ushort_t* ka = &KT[cur][(a * 32 + ln) * 72 + hi * 8];
    const ushort_t* kb = &VT[cur][(bt * 32 + ln) * 72 + hi * 8];
#pragma unroll
    for (int kc = 0; kc < 4; ++kc)
      acc = __builtin_amdgcn_mfma_f32_32x32x16_bf16(
          *(const short8*)(ka + kc * 16), *(const short8*)(kb + kc * 16), acc, 0, 0, 0);
  }
#pragma unroll
  for (int r = 0; r < 16; ++r) {
    const int kc = a * 32 + (r & 3) + 8 * (r >> 2) + 4 * hi;
    CTXB[(size_t)b * 4608 + (bt * 32 + ln) * 72 + kc] = bfb(acc[r]);
  }
}

// ---------------------------------------------------------------------------
// K5: positional lambda, block = (b, i1), grid 256, 8 waves (head m, group g).
// Round-4 schedule: 2 buffers/group, one __syncthreads per iteration,
// compiler-managed waitcnt. Private-LDS shear (no barrier). No atomics.
// ---------------------------------------------------------------------------
extern __shared__ char ldsc[];

__global__ __launch_bounds__(512) void k_pos(
    const float* __restrict__ P, const ushort_t* __restrict__ RPEB,
    const ushort_t* __restrict__ VB, const float* __restrict__ scale,
    const float* __restrict__ shift, const ushort_t* __restrict__ CTXB,
    float* __restrict__ out)
{
  float* qst = (float*)ldsc;                 // [256][33] f32 = 33792 B (later out_l)
  char* RbC = ldsc + 33792;                  // [g][buf] 9216 B each = 36864 B
  char* VbC = ldsc + 70656;                  // [g][buf] 5120 B each = 20480 B
  ushort_t* SlB = (ushort_t*)(ldsc + 91136); // 8 waves x 1280 ushorts = 20480 B
                                             // total 111616 B

  const int t = threadIdx.x;
  const int b = blockIdx.x >> 5, i1 = blockIdx.x & 31;
  const int w = t >> 6, l = t & 63, ln = l & 31, hi = l >> 5;
  const int m = w & 3, g = w >> 2;

  // stage slice i2 for group g into buffer buf (async, wave-split)
  auto stage = [&](int i2, int buf) {
    const char* rs = (const char*)RPEB + (size_t)(i2 - i1 + 31) * 9216;
    const char* vs = (const char*)VB + (size_t)(b * 32 + i2) * 5120;
    char* rd = RbC + g * 18432 + buf * 9216;
    char* vd = VbC + g * 10240 + buf * 5120;
#pragma unroll
    for (int j = 0; j < 4; ++j) {
      const int chunk = m * 4 + j;           // 0..15 within group
      const int off = chunk * 1024 + l * 16;
      if (chunk < 9)       gl16(rs + off, rd + off);
      else if (chunk < 14) gl16(vs + off - 9216, vd + off - 9216);
    }
  };

  const int i2base = g * 16;
  stage(i2base, 0);   // prologue prefetch (overlaps q staging)

  // ---- stage scaled q [256 ch][32 j1] f32 ----
  {
    const int j1 = t & 31, c0 = (t >> 5) * 16;
    const float* src = P + (size_t)b * 1024 + i1 * 32 + j1;
#pragma unroll
    for (int i = 0; i < 16; ++i) {
      const int ch = c0 + i;
      qst[ch * 33 + j1] = src[(size_t)ch * 8192] * scale[ch] + shift[ch];
    }
  }
  __syncthreads();

  // ---- q A-fragments for head m: row j1=ln, k = kc*16 + hi*8 + i ----
  short8 qf[4];
#pragma unroll
  for (int kc = 0; kc < 4; ++kc) {
    S8 s;
#pragma unroll
    for (int i = 0; i < 8; ++i)
      s.u[i] = bfb(qst[(m * 64 + kc * 16 + hi * 8 + i) * 33 + ln]);
    qf[kc] = s.v;
  }

  f32x16 sv0, sv1;
#pragma unroll
  for (int i = 0; i < 16; ++i) { sv0[i] = 0.f; sv1[i] = 0.f; }

  ushort_t* sm = SlB + w * 1280;             // private S tile [32 j1][40]

  for (int s = 0; s < 16; ++s) {
    const int cur = s & 1;
    if (s + 1 < 16) stage(i2base + s + 1, cur ^ 1);

    // T-GEMM: T[j1, dj] = sum_k q[k,j1]*rpe[di][dj][k], both dj-tiles
    f32x16 t0, t1;
#pragma unroll
    for (int i = 0; i < 16; ++i) { t0[i] = 0.f; t1[i] = 0.f; }
    {
      const ushort_t* rb = (const ushort_t*)(RbC + g * 18432 + cur * 9216);
      const ushort_t* r0 = rb + ln * 72 + hi * 8;
      const ushort_t* r1 = rb + (32 + ln) * 72 + hi * 8;
#pragma unroll
      for (int kc = 0; kc < 4; ++kc) {
        t0 = __builtin_amdgcn_mfma_f32_32x32x16_bf16(qf[kc], *(const short8*)(r0 + kc * 16), t0, 0, 0, 0);
        t1 = __builtin_amdgcn_mfma_f32_32x32x16_bf16(qf[kc], *(const short8*)(r1 + kc * 16), t1, 0, 0, 0);
      }
    }
    // shear into private Sl: S[j1][j2 = dj + j1 - 31] (within-wave only)
#pragma unroll
    for (int r = 0; r < 16; ++r) {
      const int j1 = (r & 3) + 8 * (r >> 2) + 4 * hi;
      const int j2a = ln + j1 - 31;          // dj = ln
      const int j2b = 32 + ln + j1 - 31;     // dj = 32+ln
      if ((unsigned)j2a < 32u) sm[j1 * 40 + j2a] = bfb(t0[r]);
      if ((unsigned)j2b < 32u) sm[j1 * 40 + j2b] = bfb(t1[r]);
    }
    // SV: out[j1, v] += sum_j2 S[j1,j2] * V[v,j2]  (reads own Sl; lgkmcnt only)
    {
      const ushort_t* sa = sm + ln * 40 + hi * 8;
      const ushort_t* vbp = (const ushort_t*)(VbC + g * 10240 + cur * 5120);
      const ushort_t* v0 = vbp + ln * 40 + hi * 8;
      const ushort_t* v1 = vbp + (32 + ln) * 40 + hi * 8;
      short8 sA0 = *(const short8*)(sa);
      short8 sA1 = *(const short8*)(sa + 16);
      sv0 = __builtin_amdgcn_mfma_f32_32x32x16_bf16(sA0, *(const short8*)(v0),      sv0, 0, 0, 0);
      sv0 = __builtin_amdgcn_mfma_f32_32x32x16_bf16(sA1, *(const short8*)(v0 + 16), sv0, 0, 0, 0);
      sv1 = __builtin_amdgcn_mfma_f32_32x32x16_bf16(sA0, *(const short8*)(v1),      sv1, 0, 0, 0);
      sv1 = __builtin_amdgcn_mfma_f32_32x32x16_bf16(sA1, *(const short8*)(v1 + 16), sv1, 0, 0, 0);
    }
    __syncthreads();   // buffer flip: next slice staged & visible
  }

  // ---- content epilogue: stage CTXB (all waves), group 0 adds GEMM ----
  {
    const char* cs = (const char*)CTXB + (size_t)b * 9216;
    gl16(cs + w * 1024 + l * 16, RbC + w * 1024 + l * 16);
    if (w == 0) gl16(cs + 8192 + l * 16, RbC + 8192 + l * 16);
  }
  __syncthreads();     // drains staging; RbC = ctx^T [v][72]

  float* out_l = qst;  // [256][33]
  if (g == 0) {
    const ushort_t* cb = (const ushort_t*)RbC;
    const ushort_t* c0 = cb + ln * 72 + hi * 8;
    const ushort_t* c1 = cb + (32 + ln) * 72 + hi * 8;
#pragma unroll
    for (int kc = 0; kc < 4; ++kc) {
      sv0 = __builtin_amdgcn_mfma_f32_32x32x16_bf16(qf[kc], *(const short8*)(c0 + kc * 16), sv0, 0, 0, 0);
      sv1 = __builtin_amdgcn_mfma_f32_32x32x16_bf16(qf[kc], *(const short8*)(c1 + kc * 16), sv1, 0, 0, 0);
    }
  } else {
#pragma unroll
    for (int r = 0; r < 16; ++r) {
      const int j1 = (r & 3) + 8 * (r >> 2) + 4 * hi;
      out_l[(m * 64 + ln) * 33 + j1]      = sv0[r];
      out_l[(m * 64 + 32 + ln) * 33 + j1] = sv1[r];
    }
  }
  __syncthreads();
  if (g == 0) {
#pragma unroll
    for (int r = 0; r < 16; ++r) {
      const int j1 = (r & 3) + 8 * (r >> 2) + 4 * hi;
      out_l[(m * 64 + ln) * 33 + j1]      += sv0[r];
      out_l[(m * 64 + 32 + ln) * 33 + j1] += sv1[r];
    }
  }
  __syncthreads();
  // ---- coalesced store ----
  {
    const int ch = t >> 1, jh = (t & 1) * 16;
    float* dst = out + (size_t)b * 262144 + (size_t)ch * 1024 + i1 * 32 + jh;
    const float* srow = out_l + ch * 33 + jh;
#pragma unroll
    for (int gq2 = 0; gq2 < 4; ++gq2)
      st4(dst + gq2 * 4, make_float4(srow[gq2 * 4], srow[gq2 * 4 + 1],
                                     srow[gq2 * 4 + 2], srow[gq2 * 4 + 3]));
  }
}

// ---------------------------------------------------------------------------
extern "C" void kernel_launch(void* const* d_in, const int* in_sizes, int n_in,
                              void* d_out, int out_size, void* d_ws, size_t ws_size,
                              hipStream_t stream) {
  const float* x   = (const float*)d_in[0];
  const float* wq  = (const float*)d_in[1];
  const float* gq  = (const float*)d_in[2];
  const float* bq  = (const float*)d_in[3];
  const float* wk  = (const float*)d_in[4];
  const float* gk  = (const float*)d_in[5];
  const float* bk  = (const float*)d_in[6];
  const float* wv  = (const float*)d_in[7];
  const float* rpe = (const float*)d_in[8];
  float* out = (float*)d_out;
  char* W = (char*)d_ws;

  float* P        = (float*)W;                       // 12,582,912 B
  ushort_t* KSB   = (ushort_t*)(W + 12582912);       //  1,048,576
  float* PSUM     = (float*)(W + 13631488);          //    163,840
  float* PSQ      = (float*)(W + 13795328);          //    163,840
  float* SCALE    = (float*)(W + 13959168);          //      1,280 (pad 2048)
  float* SHIFT    = (float*)(W + 13961216);          //      1,280 (pad 2048)
  ushort_t* CTXB  = (ushort_t*)(W + 13963264);       //     73,728
  ushort_t* RPEB  = (ushort_t*)(W + 14036992);       //    580,608
  ushort_t* VB    = (ushort_t*)(W + 14617600);       //  1,310,720
  ushort_t* WB    = (ushort_t*)(W + 15928320);       //    196,608
  ushort_t* XBT   = (ushort_t*)(W + 16124928);       //  4,194,304

  k_prep<<<1135, 256, 0, stream>>>(rpe, wq, wk, wv, x, RPEB, WB, XBT);
  k_projm<<<dim3(6, 64), 256, 0, stream>>>(WB, XBT, P, VB, PSUM, PSQ);
  k_bnfin<<<320, 128, 0, stream>>>(PSUM, PSQ, gq, bq, gk, bk, SCALE, SHIFT);
  k_softmax<<<512, 256, 0, stream>>>(P, SCALE, SHIFT, KSB);
  k_ctxm<<<8, 256, 0, stream>>>(KSB, VB, CTXB);

  hipFuncSetAttribute((const void*)k_pos,
                      hipFuncAttributeMaxDynamicSharedMemorySize, 111616);
  k_pos<<<256, 512, 111616, stream>>>(P, RPEB, VB, SCALE, SHIFT, CTXB, out);
}

// Round 7
// 62.015 us; speedup vs baseline: 1.4230x; 1.1724x over previous
//
#include <hip/hip_runtime.h>

// SelfAttention (lambda attention) on MI355X.
// B=8, C=256, H=W=32, n=1024, DK=64, HEADS=4, DQ=256, DV=64. SF = 64^-0.25
#define SFC 0.35355339059327373f

typedef __attribute__((ext_vector_type(8))) short short8;
typedef __attribute__((ext_vector_type(16))) float f32x16;
typedef unsigned short ushort_t;

__device__ __forceinline__ float4 ld4(const float* p) { return *reinterpret_cast<const float4*>(p); }
__device__ __forceinline__ void st4(float* p, float4 v) { *reinterpret_cast<float4*>(p) = v; }

union F4 { float4 v; float f[4]; };
union S8 { short8 v; ushort_t u[8]; };

__device__ __forceinline__ ushort_t bfb(float f) {
  union { float f; unsigned u; } a; a.f = f;
  unsigned r = a.u + 0x7FFFu + ((a.u >> 16) & 1u);   // RNE f32->bf16
  return (ushort_t)(r >> 16);
}

__device__ __forceinline__ void gl16(const void* g, void* l) {
  __builtin_amdgcn_global_load_lds(
      (const __attribute__((address_space(1))) unsigned int*)g,
      (__attribute__((address_space(3))) unsigned int*)l, 16, 0, 0);
}

// ---------------------------------------------------------------------------
// K0: prep.
// blocks 0..62:  rpe -> RPEB2 fragment-major bf16:
//                RPEB2[di][tkc = tau*4+kc][lane 0..63][8]  (4096 ushorts/di)
//                frag elem: dj = tau*32 + (l&31), k = kc*16 + (l>>5)*8 + i
// blocks 63..110: Wq/Wk/Wv -> WB bf16 [384][256]
// blocks 111..1134: x -> XBT bf16 [b*1024+n][256 c]
// ---------------------------------------------------------------------------
__global__ __launch_bounds__(256) void k_prep(
    const float* __restrict__ rpe, const float* __restrict__ wq,
    const float* __restrict__ wk, const float* __restrict__ wv,
    const float* __restrict__ x, ushort_t* __restrict__ RPEB2,
    ushort_t* __restrict__ WB, ushort_t* __restrict__ XBT)
{
  const int bx = blockIdx.x, t = threadIdx.x;
  if (bx < 63) {
    const int di = bx;
#pragma unroll
    for (int it = 0; it < 2; ++it) {
      const int slot = t + it * 256;           // 0..511
      const int tkc = slot >> 6;               // tau*4 + kc
      const int l = slot & 63, lnp = l & 31, hip = l >> 5;
      const int dj = (tkc >> 2) * 32 + lnp;
      const int k = (tkc & 3) * 16 + hip * 8;
      S8 o;
      if (dj < 63) {
        const float* s = rpe + (size_t)di * 4032 + dj * 64 + k;
        float4 a = ld4(s), b = ld4(s + 4);
        o.u[0] = bfb(a.x); o.u[1] = bfb(a.y); o.u[2] = bfb(a.z); o.u[3] = bfb(a.w);
        o.u[4] = bfb(b.x); o.u[5] = bfb(b.y); o.u[6] = bfb(b.z); o.u[7] = bfb(b.w);
      } else {
#pragma unroll
        for (int i = 0; i < 8; ++i) o.u[i] = 0;
      }
      *(short8*)(RPEB2 + (size_t)di * 4096 + tkc * 512 + l * 8) = o.v;
    }
  } else if (bx < 111) {
    const int cc = (bx - 63) * 256 + t;        // 0..12287
    const int o = cc >> 5, k8 = (cc & 31) * 8;
    const float* src = (o < 256) ? (wq + o * 256)
                      : (o < 320) ? (wk + (o - 256) * 256)
                                  : (wv + (o - 320) * 256);
    float4 a = ld4(src + k8), b = ld4(src + k8 + 4);
    S8 s;
    s.u[0] = bfb(a.x); s.u[1] = bfb(a.y); s.u[2] = bfb(a.z); s.u[3] = bfb(a.w);
    s.u[4] = bfb(b.x); s.u[5] = bfb(b.y); s.u[6] = bfb(b.z); s.u[7] = bfb(b.w);
    *(short8*)(WB + (size_t)o * 256 + k8) = s.v;
  } else {
    const int id = (bx - 111) * 256 + t;       // 0..262143
    const int ng = id & 8191, c8 = id >> 13;   // n global, c chunk
    const int bb = ng >> 10, nn = ng & 1023;
    const float* src = x + (size_t)bb * 262144 + (size_t)(c8 * 8) * 1024 + nn;
    S8 s;
#pragma unroll
    for (int j = 0; j < 8; ++j) s.u[j] = bfb(src[(size_t)j * 1024]);
    *(short8*)(XBT + (size_t)ng * 256 + c8 * 8) = s.v;
  }
}

// ---------------------------------------------------------------------------
// K1: projection GEMM via MFMA: P[o][col] = sum_c WB[o][c] * XBT[col][c].
// bm==5 (V rows) emits VB2 fragment-major bf16:
//   VB2[b][i2][tauv][c][lane][8]; elem: v = tauv*32+(l&31), j2 = c*16+(l>>5)*8+i
// bm<5: per-wave column sums -> non-atomic partials PSUM/PSQ[o][128].
// ---------------------------------------------------------------------------
__global__ __launch_bounds__(256) void k_projm(
    const ushort_t* __restrict__ WB, const ushort_t* __restrict__ XBT,
    float* __restrict__ P, ushort_t* __restrict__ VB2,
    float* __restrict__ PSUM, float* __restrict__ PSQ)
{
  __shared__ ushort_t At[64 * 72];
  __shared__ ushort_t Bt[128 * 72];
  const int t = threadIdx.x;
  const int bm = blockIdx.x, bn = blockIdx.y;
  const int o0 = bm * 64, col0 = bn * 128;
  const int w = t >> 6, l = t & 63, ln = l & 31, hi = l >> 5;
  const int wm = w & 1, wn = w >> 1;

  f32x16 acc0, acc1;
#pragma unroll
  for (int i = 0; i < 16; ++i) { acc0[i] = 0.f; acc1[i] = 0.f; }

  for (int k0 = 0; k0 < 256; k0 += 64) {
    __syncthreads();
#pragma unroll
    for (int i = 0; i < 2; ++i) {
      const int c = t + i * 256, row = c >> 3, k8 = (c & 7) * 8;
      *(short8*)(At + row * 72 + k8) =
          *(const short8*)(WB + (size_t)(o0 + row) * 256 + k0 + k8);
    }
#pragma unroll
    for (int i = 0; i < 4; ++i) {
      const int c = t + i * 256, row = c >> 3, k8 = (c & 7) * 8;
      *(short8*)(Bt + row * 72 + k8) =
          *(const short8*)(XBT + (size_t)(col0 + row) * 256 + k0 + k8);
    }
    __syncthreads();
    const ushort_t* ka  = At + (wm * 32 + ln) * 72 + hi * 8;
    const ushort_t* kb0 = Bt + (wn * 64 + ln) * 72 + hi * 8;
    const ushort_t* kb1 = Bt + (wn * 64 + 32 + ln) * 72 + hi * 8;
#pragma unroll
    for (int kc = 0; kc < 4; ++kc) {
      short8 a = *(const short8*)(ka + kc * 16);
      acc0 = __builtin_amdgcn_mfma_f32_32x32x16_bf16(a, *(const short8*)(kb0 + kc * 16), acc0, 0, 0, 0);
      acc1 = __builtin_amdgcn_mfma_f32_32x32x16_bf16(a, *(const short8*)(kb1 + kc * 16), acc1, 0, 0, 0);
    }
  }

#pragma unroll
  for (int r = 0; r < 16; ++r) {
    const int o = o0 + wm * 32 + (r & 3) + 8 * (r >> 2) + 4 * hi;
    float* dst = P + (size_t)o * 8192 + col0 + wn * 64 + ln;
    dst[0]  = acc0[r];
    dst[32] = acc1[r];
  }
  if (bm == 5) {
    const int b2 = bn >> 3;
    const int n0 = (bn & 7) * 128 + wn * 64 + ln;   // n for acc0 cols
#pragma unroll
    for (int r = 0; r < 16; ++r) {
      const int v = wm * 32 + (r & 3) + 8 * (r >> 2) + 4 * hi;
#pragma unroll
      for (int half = 0; half < 2; ++half) {
        const int n = n0 + half * 32;
        const int i2 = n >> 5, j2 = n & 31;
        const float val = half ? acc1[r] : acc0[r];
        VB2[(((size_t)(b2 * 32 + i2) * 2 + wm) * 2 + (j2 >> 4)) * 512
            + ((v & 31) + 32 * ((j2 >> 3) & 1)) * 8 + (j2 & 7)] = bfb(val);
      }
    }
  } else {
#pragma unroll
    for (int r = 0; r < 16; ++r) {
      float s1 = acc0[r] + acc1[r];
      float s2 = acc0[r] * acc0[r] + acc1[r] * acc1[r];
#pragma unroll
      for (int off = 1; off < 32; off <<= 1) {
        s1 += __shfl_xor(s1, off, 64);
        s2 += __shfl_xor(s2, off, 64);
      }
      if (ln == 0) {
        const int o = o0 + wm * 32 + (r & 3) + 8 * (r >> 2) + 4 * hi;
        PSUM[o * 128 + bn * 2 + wn] = s1;
        PSQ [o * 128 + bn * 2 + wn] = s2;
      }
    }
  }
}

// ---------------------------------------------------------------------------
// K2: BN finalize: reduce 128 partials per channel -> SCALE/SHIFT.
// ---------------------------------------------------------------------------
__global__ __launch_bounds__(128) void k_bnfin(
    const float* __restrict__ PSUM, const float* __restrict__ PSQ,
    const float* __restrict__ gq, const float* __restrict__ bq,
    const float* __restrict__ gk, const float* __restrict__ bk,
    float* __restrict__ scale, float* __restrict__ shift)
{
  const int ch = blockIdx.x, t = threadIdx.x;
  float s1 = PSUM[ch * 128 + t];
  float s2 = PSQ[ch * 128 + t];
#pragma unroll
  for (int off = 1; off < 64; off <<= 1) {
    s1 += __shfl_xor(s1, off, 64);
    s2 += __shfl_xor(s2, off, 64);
  }
  __shared__ float red[4];
  if ((t & 63) == 0) { red[t >> 6] = s1; red[2 + (t >> 6)] = s2; }
  __syncthreads();
  if (t == 0) {
    s1 = red[0] + red[1];
    s2 = red[2] + red[3];
    const float mu = s1 * (1.0f / 8192.0f);
    const float var = s2 * (1.0f / 8192.0f) - mu * mu;
    const float rsig = rsqrtf(var + 1e-5f);
    float g, be;
    if (ch < 256) { g = gq[ch]; be = bq[ch]; }
    else          { g = gk[ch - 256]; be = bk[ch - 256]; }
    const float sc = rsig * g * SFC;
    scale[ch] = sc;
    shift[ch] = be * SFC - mu * sc;
  }
}

// ---------------------------------------------------------------------------
// K3: softmax over n per (b, k-channel). Writes KSB bf16 [b][kc][1024].
// ---------------------------------------------------------------------------
__global__ __launch_bounds__(256) void k_softmax(
    const float* __restrict__ P, const float* __restrict__ scale,
    const float* __restrict__ shift, ushort_t* __restrict__ KSB)
{
  const int b = blockIdx.x >> 6, kc = blockIdx.x & 63;
  const int ch = 256 + kc;
  const float sc = scale[ch], sh = shift[ch];
  const float4* row = (const float4*)(P + (size_t)ch * 8192 + b * 1024);
  float4 v = row[threadIdx.x];
  float y0 = v.x * sc + sh, y1 = v.y * sc + sh;
  float y2 = v.z * sc + sh, y3 = v.w * sc + sh;
  float m = fmaxf(fmaxf(y0, y1), fmaxf(y2, y3));
#pragma unroll
  for (int off = 32; off; off >>= 1) m = fmaxf(m, __shfl_xor(m, off, 64));
  __shared__ float red[8];
  const int w = threadIdx.x >> 6, lane = threadIdx.x & 63;
  if (lane == 0) red[w] = m;
  __syncthreads();
  m = fmaxf(fmaxf(red[0], red[1]), fmaxf(red[2], red[3]));
  const float e0 = __expf(y0 - m), e1 = __expf(y1 - m);
  const float e2 = __expf(y2 - m), e3 = __expf(y3 - m);
  float su = e0 + e1 + e2 + e3;
#pragma unroll
  for (int off = 32; off; off >>= 1) su += __shfl_xor(su, off, 64);
  if (lane == 0) red[4 + w] = su;
  __syncthreads();
  const float inv = 1.0f / (red[4] + red[5] + red[6] + red[7]);
  ushort4 u;
  u.x = bfb(e0 * inv); u.y = bfb(e1 * inv);
  u.z = bfb(e2 * inv); u.w = bfb(e3 * inv);
  ((ushort4*)(KSB + (size_t)(b * 64 + kc) * 1024))[threadIdx.x] = u;
}

// ---------------------------------------------------------------------------
// K4: content context via MFMA: ctx[k][v] = sum_n ks[k][n]*v[v][n] per b.
// KS staged in LDS; V fragments loaded REG-DIRECT from VB2.
// Writes CTXB bf16 [b][v][72 k-pad]. Grid 8, 4 waves (kc-tile a, vc-tile bt).
// ---------------------------------------------------------------------------
__global__ __launch_bounds__(256) void k_ctxm(
    const ushort_t* __restrict__ KSB, const ushort_t* __restrict__ VB2,
    ushort_t* __restrict__ CTXB)
{
  __shared__ ushort_t KT[2][64 * 72];
  const int b = blockIdx.x, t = threadIdx.x;
  const int w = t >> 6, l = t & 63, ln = l & 31, hi = l >> 5;
  const int a = w & 1, bt = w >> 1;

  auto stageK = [&](int ch, int buf) {
    const int n0 = ch * 64;
#pragma unroll
    for (int it = 0; it < 2; ++it) {
      const int idx = t + it * 256;
      const int row = idx >> 3, seg = idx & 7;
      *(short8*)(&KT[buf][row * 72 + seg * 8]) =
          *(const short8*)(KSB + (size_t)(b * 64 + row) * 1024 + n0 + seg * 8);
    }
  };

  f32x16 acc;
#pragma unroll
  for (int i = 0; i < 16; ++i) acc[i] = 0.f;

  stageK(0, 0);
  for (int ch = 0; ch < 16; ++ch) {
    const int cur = ch & 1;
    __syncthreads();
    if (ch + 1 < 16) stageK(ch + 1, cur ^ 1);
    const ushort_t* ka = &KT[cur][(a * 32 + ln) * 72 + hi * 8];
#pragma unroll
    for (int cc = 0; cc < 4; ++cc) {
      const int i2 = ch * 2 + (cc >> 1), c = cc & 1;
      short8 bf = *(const short8*)(VB2 +
          (((size_t)(b * 32 + i2) * 2 + bt) * 2 + c) * 512 + l * 8);
      acc = __builtin_amdgcn_mfma_f32_32x32x16_bf16(
          *(const short8*)(ka + cc * 16), bf, acc, 0, 0, 0);
    }
  }
#pragma unroll
  for (int r = 0; r < 16; ++r) {
    const int kc = a * 32 + (r & 3) + 8 * (r >> 2) + 4 * hi;
    CTXB[(size_t)b * 4608 + (bt * 32 + ln) * 72 + kc] = bfb(acc[r]);
  }
}

// ---------------------------------------------------------------------------
// K5: positional lambda, block = (b, i1), grid 256, 8 waves (head m, group g).
// BARRIER-FREE main loop: rpe/V fragments loaded reg-direct from
// fragment-major RPEB2/VB2 (coalesced, L1/L2-hot); 2-deep rpe reg prefetch.
// LDS only for per-wave shear tile Sl + q staging + ctx epilogue.
// ---------------------------------------------------------------------------
extern __shared__ char ldsc[];

__global__ __launch_bounds__(512) void k_pos(
    const float* __restrict__ P, const ushort_t* __restrict__ RPEB2,
    const ushort_t* __restrict__ VB2, const float* __restrict__ scale,
    const float* __restrict__ shift, const ushort_t* __restrict__ CTXB,
    float* __restrict__ out)
{
  float* qst = (float*)ldsc;                   // [256][33] f32 = 33792 (later out_l)
  ushort_t* SlB = (ushort_t*)(ldsc + 33792);   // 8 waves x [32][40] = 20480
  char* CtxL = ldsc + 54272;                   // 9216 (ctx^T [v][72] bf16)
                                               // total 63488

  const int t = threadIdx.x;
  const int b = blockIdx.x >> 5, i1 = blockIdx.x & 31;
  const int w = t >> 6, l = t & 63, ln = l & 31, hi = l >> 5;
  const int m = w & 3, g = w >> 2;

  // ---- issue ctx staging now; consumed after the post-loop barrier ----
  {
    const char* cs = (const char*)CTXB + (size_t)b * 9216;
    gl16(cs + w * 1024 + l * 16, CtxL + w * 1024 + l * 16);
    if (w == 0) gl16(cs + 8192 + l * 16, CtxL + 8192 + l * 16);
  }

  const ushort_t* rbase = RPEB2 + (size_t)(g * 16 - i1 + 31) * 4096;
  const ushort_t* vbase = VB2 + (size_t)(b * 32 + g * 16) * 2048;

  // prologue prefetch: rpe frags for s=0
  short8 rA[8], rB[8];
#pragma unroll
  for (int f = 0; f < 8; ++f) rA[f] = *(const short8*)(rbase + f * 512 + l * 8);

  // ---- stage scaled q [256 ch][32 j1] f32 ----
  {
    const int j1 = t & 31, c0 = (t >> 5) * 16;
    const float* src = P + (size_t)b * 1024 + i1 * 32 + j1;
#pragma unroll
    for (int i = 0; i < 16; ++i) {
      const int ch = c0 + i;
      qst[ch * 33 + j1] = src[(size_t)ch * 8192] * scale[ch] + shift[ch];
    }
  }
  __syncthreads();

  // ---- q fragments for head m: B/A layout row j1=ln, k = kc*16 + hi*8 + i ----
  short8 qf[4];
#pragma unroll
  for (int kc = 0; kc < 4; ++kc) {
    S8 s;
#pragma unroll
    for (int i = 0; i < 8; ++i)
      s.u[i] = bfb(qst[(m * 64 + kc * 16 + hi * 8 + i) * 33 + ln]);
    qf[kc] = s.v;
  }

  f32x16 sv0, sv1;
#pragma unroll
  for (int i = 0; i < 16; ++i) { sv0[i] = 0.f; sv1[i] = 0.f; }

  ushort_t* sm = SlB + w * 1280;               // private S tile [32 j1][40]

  auto body = [&](int s, const short8* R) {
    // V fragments for this i2 (reg-direct, coalesced)
    const ushort_t* vp = vbase + (size_t)s * 2048 + l * 8;
    short8 v00 = *(const short8*)(vp);
    short8 v01 = *(const short8*)(vp + 512);
    short8 v10 = *(const short8*)(vp + 1024);
    short8 v11 = *(const short8*)(vp + 1536);
    // T-GEMM: T[j1][dj] = sum_k q[k][j1]*rpe[di][dj][k]
    f32x16 t0, t1;
#pragma unroll
    for (int i = 0; i < 16; ++i) { t0[i] = 0.f; t1[i] = 0.f; }
#pragma unroll
    for (int kc = 0; kc < 4; ++kc) {
      t0 = __builtin_amdgcn_mfma_f32_32x32x16_bf16(qf[kc], R[kc],     t0, 0, 0, 0);
      t1 = __builtin_amdgcn_mfma_f32_32x32x16_bf16(qf[kc], R[4 + kc], t1, 0, 0, 0);
    }
    // shear into private Sl: S[j1][j2 = dj + j1 - 31]
#pragma unroll
    for (int r = 0; r < 16; ++r) {
      const int j1 = (r & 3) + 8 * (r >> 2) + 4 * hi;
      const int j2a = ln + j1 - 31;            // dj = ln
      const int j2b = 32 + ln + j1 - 31;       // dj = 32+ln
      if ((unsigned)j2a < 32u) sm[j1 * 40 + j2a] = bfb(t0[r]);
      if ((unsigned)j2b < 32u) sm[j1 * 40 + j2b] = bfb(t1[r]);
    }
    // SV: out[j1][v] += sum_j2 S[j1][j2] * V[v][j2]
    const ushort_t* sa = sm + ln * 40 + hi * 8;
    short8 sA0 = *(const short8*)(sa);
    short8 sA1 = *(const short8*)(sa + 16);
    sv0 = __builtin_amdgcn_mfma_f32_32x32x16_bf16(sA0, v00, sv0, 0, 0, 0);
    sv0 = __builtin_amdgcn_mfma_f32_32x32x16_bf16(sA1, v01, sv0, 0, 0, 0);
    sv1 = __builtin_amdgcn_mfma_f32_32x32x16_bf16(sA0, v10, sv1, 0, 0, 0);
    sv1 = __builtin_amdgcn_mfma_f32_32x32x16_bf16(sA1, v11, sv1, 0, 0, 0);
  };

  for (int s = 0; s < 16; s += 2) {
    {  // prefetch s+1 into rB (always valid: s <= 14)
      const ushort_t* rn = rbase + (size_t)(s + 1) * 4096;
#pragma unroll
      for (int f = 0; f < 8; ++f) rB[f] = *(const short8*)(rn + f * 512 + l * 8);
    }
    body(s, rA);
    if (s + 2 < 16) {  // prefetch s+2 into rA
      const ushort_t* rn = rbase + (size_t)(s + 2) * 4096;
#pragma unroll
      for (int f = 0; f < 8; ++f) rA[f] = *(const short8*)(rn + f * 512 + l * 8);
    }
    body(s + 1, rB);
  }

  __syncthreads();   // loop done; drains ctx gl16; Sl & qst dead

  float* out_l = qst;  // [256][33]
  if (g == 0) {
    // content GEMM: out += q^T * ctx  (ctx^T [v][72] in CtxL)
    const ushort_t* cb = (const ushort_t*)CtxL;
    const ushort_t* c0 = cb + ln * 72 + hi * 8;
    const ushort_t* c1 = cb + (32 + ln) * 72 + hi * 8;
#pragma unroll
    for (int kc = 0; kc < 4; ++kc) {
      sv0 = __builtin_amdgcn_mfma_f32_32x32x16_bf16(qf[kc], *(const short8*)(c0 + kc * 16), sv0, 0, 0, 0);
      sv1 = __builtin_amdgcn_mfma_f32_32x32x16_bf16(qf[kc], *(const short8*)(c1 + kc * 16), sv1, 0, 0, 0);
    }
  } else {
#pragma unroll
    for (int r = 0; r < 16; ++r) {
      const int j1 = (r & 3) + 8 * (r >> 2) + 4 * hi;
      out_l[(m * 64 + ln) * 33 + j1]      = sv0[r];
      out_l[(m * 64 + 32 + ln) * 33 + j1] = sv1[r];
    }
  }
  __syncthreads();
  if (g == 0) {
#pragma unroll
    for (int r = 0; r < 16; ++r) {
      const int j1 = (r & 3) + 8 * (r >> 2) + 4 * hi;
      out_l[(m * 64 + ln) * 33 + j1]      += sv0[r];
      out_l[(m * 64 + 32 + ln) * 33 + j1] += sv1[r];
    }
  }
  __syncthreads();
  // ---- coalesced store ----
  {
    const int ch = t >> 1, jh = (t & 1) * 16;
    float* dst = out + (size_t)b * 262144 + (size_t)ch * 1024 + i1 * 32 + jh;
    const float* srow = out_l + ch * 33 + jh;
#pragma unroll
    for (int gq2 = 0; gq2 < 4; ++gq2)
      st4(dst + gq2 * 4, make_float4(srow[gq2 * 4], srow[gq2 * 4 + 1],
                                     srow[gq2 * 4 + 2], srow[gq2 * 4 + 3]));
  }
}

// ---------------------------------------------------------------------------
extern "C" void kernel_launch(void* const* d_in, const int* in_sizes, int n_in,
                              void* d_out, int out_size, void* d_ws, size_t ws_size,
                              hipStream_t stream) {
  const float* x   = (const float*)d_in[0];
  const float* wq  = (const float*)d_in[1];
  const float* gq  = (const float*)d_in[2];
  const float* bq  = (const float*)d_in[3];
  const float* wk  = (const float*)d_in[4];
  const float* gk  = (const float*)d_in[5];
  const float* bk  = (const float*)d_in[6];
  const float* wv  = (const float*)d_in[7];
  const float* rpe = (const float*)d_in[8];
  float* out = (float*)d_out;
  char* W = (char*)d_ws;

  float* P        = (float*)W;                       // 12,582,912 B
  ushort_t* KSB   = (ushort_t*)(W + 12582912);       //  1,048,576
  float* PSUM     = (float*)(W + 13631488);          //    163,840
  float* PSQ      = (float*)(W + 13795328);          //    163,840
  float* SCALE    = (float*)(W + 13959168);          //      1,280 (pad 2048)
  float* SHIFT    = (float*)(W + 13961216);          //      1,280 (pad 2048)
  ushort_t* CTXB  = (ushort_t*)(W + 13963264);       //     73,728
  ushort_t* RPEB2 = (ushort_t*)(W + 14036992);       //    516,096
  ushort_t* VB2   = (ushort_t*)(W + 14553088);       //  1,048,576
  ushort_t* WB    = (ushort_t*)(W + 15601664);       //    196,608
  ushort_t* XBT   = (ushort_t*)(W + 15798272);       //  4,194,304

  k_prep<<<1135, 256, 0, stream>>>(rpe, wq, wk, wv, x, RPEB2, WB, XBT);
  k_projm<<<dim3(6, 64), 256, 0, stream>>>(WB, XBT, P, VB2, PSUM, PSQ);
  k_bnfin<<<320, 128, 0, stream>>>(PSUM, PSQ, gq, bq, gk, bk, SCALE, SHIFT);
  k_softmax<<<512, 256, 0, stream>>>(P, SCALE, SHIFT, KSB);
  k_ctxm<<<8, 256, 0, stream>>>(KSB, VB2, CTXB);

  hipFuncSetAttribute((const void*)k_pos,
                      hipFuncAttributeMaxDynamicSharedMemorySize, 63488);
  k_pos<<<256, 512, 63488, stream>>>(P, RPEB2, VB2, SCALE, SHIFT, CTXB, out);
}

// Round 8
// 59.413 us; speedup vs baseline: 1.4854x; 1.0438x over previous
//
#include <hip/hip_runtime.h>

// SelfAttention (lambda attention) on MI355X.
// B=8, C=256, H=W=32, n=1024, DK=64, HEADS=4, DQ=256, DV=64. SF = 64^-0.25
#define SFC 0.35355339059327373f

typedef __attribute__((ext_vector_type(8))) short short8;
typedef __attribute__((ext_vector_type(16))) float f32x16;
typedef unsigned short ushort_t;

__device__ __forceinline__ float4 ld4(const float* p) { return *reinterpret_cast<const float4*>(p); }
__device__ __forceinline__ void st4(float* p, float4 v) { *reinterpret_cast<float4*>(p) = v; }

union F4 { float4 v; float f[4]; };
union S8 { short8 v; ushort_t u[8]; };

__device__ __forceinline__ ushort_t bfb(float f) {
  union { float f; unsigned u; } a; a.f = f;
  unsigned r = a.u + 0x7FFFu + ((a.u >> 16) & 1u);   // RNE f32->bf16
  return (ushort_t)(r >> 16);
}
__device__ __forceinline__ float bf2f(ushort_t u) {
  union { unsigned u; float f; } a; a.u = (unsigned)u << 16; return a.f;
}

__device__ __forceinline__ void gl16(const void* g, void* l) {
  __builtin_amdgcn_global_load_lds(
      (const __attribute__((address_space(1))) unsigned int*)g,
      (__attribute__((address_space(3))) unsigned int*)l, 16, 0, 0);
}

// ---------------------------------------------------------------------------
// K0: prep.
// blocks 0..62:  rpe -> RPEB2 fragment-major bf16 [di][tkc][lane][8]
// blocks 63..110: Wq/Wk/Wv -> WB bf16 [384][256]
// blocks 111..1134: x -> XBT bf16 [b*1024+n][256 c]
// ---------------------------------------------------------------------------
__global__ __launch_bounds__(256) void k_prep(
    const float* __restrict__ rpe, const float* __restrict__ wq,
    const float* __restrict__ wk, const float* __restrict__ wv,
    const float* __restrict__ x, ushort_t* __restrict__ RPEB2,
    ushort_t* __restrict__ WB, ushort_t* __restrict__ XBT)
{
  const int bx = blockIdx.x, t = threadIdx.x;
  if (bx < 63) {
    const int di = bx;
#pragma unroll
    for (int it = 0; it < 2; ++it) {
      const int slot = t + it * 256;           // 0..511
      const int tkc = slot >> 6;               // tau*4 + kc
      const int l = slot & 63, lnp = l & 31, hip = l >> 5;
      const int dj = (tkc >> 2) * 32 + lnp;
      const int k = (tkc & 3) * 16 + hip * 8;
      S8 o;
      if (dj < 63) {
        const float* s = rpe + (size_t)di * 4032 + dj * 64 + k;
        float4 a = ld4(s), b = ld4(s + 4);
        o.u[0] = bfb(a.x); o.u[1] = bfb(a.y); o.u[2] = bfb(a.z); o.u[3] = bfb(a.w);
        o.u[4] = bfb(b.x); o.u[5] = bfb(b.y); o.u[6] = bfb(b.z); o.u[7] = bfb(b.w);
      } else {
#pragma unroll
        for (int i = 0; i < 8; ++i) o.u[i] = 0;
      }
      *(short8*)(RPEB2 + (size_t)di * 4096 + tkc * 512 + l * 8) = o.v;
    }
  } else if (bx < 111) {
    const int cc = (bx - 63) * 256 + t;        // 0..12287
    const int o = cc >> 5, k8 = (cc & 31) * 8;
    const float* src = (o < 256) ? (wq + o * 256)
                      : (o < 320) ? (wk + (o - 256) * 256)
                                  : (wv + (o - 320) * 256);
    float4 a = ld4(src + k8), b = ld4(src + k8 + 4);
    S8 s;
    s.u[0] = bfb(a.x); s.u[1] = bfb(a.y); s.u[2] = bfb(a.z); s.u[3] = bfb(a.w);
    s.u[4] = bfb(b.x); s.u[5] = bfb(b.y); s.u[6] = bfb(b.z); s.u[7] = bfb(b.w);
    *(short8*)(WB + (size_t)o * 256 + k8) = s.v;
  } else {
    const int id = (bx - 111) * 256 + t;       // 0..262143
    const int ng = id & 8191, c8 = id >> 13;   // n global, c chunk
    const int bb = ng >> 10, nn = ng & 1023;
    const float* src = x + (size_t)bb * 262144 + (size_t)(c8 * 8) * 1024 + nn;
    S8 s;
#pragma unroll
    for (int j = 0; j < 8; ++j) s.u[j] = bfb(src[(size_t)j * 1024]);
    *(short8*)(XBT + (size_t)ng * 256 + c8 * 8) = s.v;
  }
}

// ---------------------------------------------------------------------------
// K1: projection GEMM via MFMA. Outputs:
//   bm<4 (q rows): QB fragment-major bf16 [b][i1][m][kc][lane][8] (unscaled)
//   bm==4 (k rows): Pk f32 [64][8192]
//   bm==5 (v rows): VB2 fragment-major bf16
//   bm<5: per-wave column-sum partials PSUM/PSQ[o][128] (non-atomic)
// ---------------------------------------------------------------------------
__global__ __launch_bounds__(256) void k_projm(
    const ushort_t* __restrict__ WB, const ushort_t* __restrict__ XBT,
    float* __restrict__ Pk, ushort_t* __restrict__ QB,
    ushort_t* __restrict__ VB2, float* __restrict__ PSUM,
    float* __restrict__ PSQ)
{
  __shared__ ushort_t At[64 * 72];
  __shared__ ushort_t Bt[128 * 72];
  const int t = threadIdx.x;
  const int bm = blockIdx.x, bn = blockIdx.y;
  const int o0 = bm * 64, col0 = bn * 128;
  const int w = t >> 6, l = t & 63, ln = l & 31, hi = l >> 5;
  const int wm = w & 1, wn = w >> 1;

  f32x16 acc0, acc1;
#pragma unroll
  for (int i = 0; i < 16; ++i) { acc0[i] = 0.f; acc1[i] = 0.f; }

  for (int k0 = 0; k0 < 256; k0 += 64) {
    __syncthreads();
#pragma unroll
    for (int i = 0; i < 2; ++i) {
      const int c = t + i * 256, row = c >> 3, k8 = (c & 7) * 8;
      *(short8*)(At + row * 72 + k8) =
          *(const short8*)(WB + (size_t)(o0 + row) * 256 + k0 + k8);
    }
#pragma unroll
    for (int i = 0; i < 4; ++i) {
      const int c = t + i * 256, row = c >> 3, k8 = (c & 7) * 8;
      *(short8*)(Bt + row * 72 + k8) =
          *(const short8*)(XBT + (size_t)(col0 + row) * 256 + k0 + k8);
    }
    __syncthreads();
    const ushort_t* ka  = At + (wm * 32 + ln) * 72 + hi * 8;
    const ushort_t* kb0 = Bt + (wn * 64 + ln) * 72 + hi * 8;
    const ushort_t* kb1 = Bt + (wn * 64 + 32 + ln) * 72 + hi * 8;
#pragma unroll
    for (int kc = 0; kc < 4; ++kc) {
      short8 a = *(const short8*)(ka + kc * 16);
      acc0 = __builtin_amdgcn_mfma_f32_32x32x16_bf16(a, *(const short8*)(kb0 + kc * 16), acc0, 0, 0, 0);
      acc1 = __builtin_amdgcn_mfma_f32_32x32x16_bf16(a, *(const short8*)(kb1 + kc * 16), acc1, 0, 0, 0);
    }
  }

  if (bm == 5) {
    const int b2 = bn >> 3;
    const int n0 = (bn & 7) * 128 + wn * 64 + ln;
#pragma unroll
    for (int r = 0; r < 16; ++r) {
      const int v = wm * 32 + (r & 3) + 8 * (r >> 2) + 4 * hi;
#pragma unroll
      for (int half = 0; half < 2; ++half) {
        const int n = n0 + half * 32;
        const int i2 = n >> 5, j2 = n & 31;
        const float val = half ? acc1[r] : acc0[r];
        VB2[(((size_t)(b2 * 32 + i2) * 2 + wm) * 2 + (j2 >> 4)) * 512
            + ((v & 31) + 32 * ((j2 >> 3) & 1)) * 8 + (j2 & 7)] = bfb(val);
      }
    }
  } else {
    if (bm == 4) {
      // k rows -> Pk f32
#pragma unroll
      for (int r = 0; r < 16; ++r) {
        const int o = o0 + wm * 32 + (r & 3) + 8 * (r >> 2) + 4 * hi;  // 256..319
        float* dst = Pk + (size_t)(o - 256) * 8192 + col0 + wn * 64 + ln;
        dst[0]  = acc0[r];
        dst[32] = acc1[r];
      }
    } else {
      // q rows -> QB fragment-major bf16 (unscaled)
      const int kcq = 2 * wm;   // + (r>>3)&1
#pragma unroll
      for (int r = 0; r < 16; ++r) {
        const int kc = kcq + ((r >> 3) & 1);
        const int lq = ln + 32 * ((r >> 2) & 1);
        const int iq = (r & 3) + 4 * hi;
#pragma unroll
        for (int half = 0; half < 2; ++half) {
          const int n = col0 + wn * 64 + half * 32 + ln;
          const int bq_ = n >> 10, i1q = (n >> 5) & 31;
          const float val = half ? acc1[r] : acc0[r];
          QB[(((size_t)(bq_ * 32 + i1q) * 4 + bm) * 4 + kc) * 512 + lq * 8 + iq] =
              bfb(val);
        }
      }
    }
    // BN partials (q and k rows)
#pragma unroll
    for (int r = 0; r < 16; ++r) {
      float s1 = acc0[r] + acc1[r];
      float s2 = acc0[r] * acc0[r] + acc1[r] * acc1[r];
#pragma unroll
      for (int off = 1; off < 32; off <<= 1) {
        s1 += __shfl_xor(s1, off, 64);
        s2 += __shfl_xor(s2, off, 64);
      }
      if (ln == 0) {
        const int o = o0 + wm * 32 + (r & 3) + 8 * (r >> 2) + 4 * hi;
        PSUM[o * 128 + bn * 2 + wn] = s1;
        PSQ [o * 128 + bn * 2 + wn] = s2;
      }
    }
  }
}

// ---------------------------------------------------------------------------
// K2: grid 768.
// blocks 0..511 (b, kc): inline BN finalize for k-channel + softmax over n.
// blocks 512..767: finalize q-channel SCALE/SHIFT from partials.
// ---------------------------------------------------------------------------
__global__ __launch_bounds__(256) void k_softmax(
    const float* __restrict__ Pk, const float* __restrict__ PSUM,
    const float* __restrict__ PSQ, const float* __restrict__ gq,
    const float* __restrict__ bq, const float* __restrict__ gk,
    const float* __restrict__ bk, float* __restrict__ SCALE,
    float* __restrict__ SHIFT, ushort_t* __restrict__ KSB)
{
  __shared__ float red[8];
  __shared__ float scsh[2];
  const int t = threadIdx.x;

  if (blockIdx.x >= 512) {
    const int ch = blockIdx.x - 512;     // q channel 0..255
    float s1 = 0.f, s2 = 0.f;
    if (t < 128) { s1 = PSUM[ch * 128 + t]; s2 = PSQ[ch * 128 + t]; }
#pragma unroll
    for (int off = 1; off < 64; off <<= 1) {
      s1 += __shfl_xor(s1, off, 64);
      s2 += __shfl_xor(s2, off, 64);
    }
    if ((t & 63) == 0) { red[t >> 6] = s1; red[4 + (t >> 6)] = s2; }
    __syncthreads();
    if (t == 0) {
      s1 = red[0] + red[1] + red[2] + red[3];
      s2 = red[4] + red[5] + red[6] + red[7];
      const float mu = s1 * (1.0f / 8192.0f);
      const float var = s2 * (1.0f / 8192.0f) - mu * mu;
      const float sc = rsqrtf(var + 1e-5f) * gq[ch] * SFC;
      SCALE[ch] = sc;
      SHIFT[ch] = bq[ch] * SFC - mu * sc;
    }
    return;
  }

  const int b = blockIdx.x >> 6, kc = blockIdx.x & 63;
  {
    const int ch = 256 + kc;
    float s1 = 0.f, s2 = 0.f;
    if (t < 128) { s1 = PSUM[ch * 128 + t]; s2 = PSQ[ch * 128 + t]; }
#pragma unroll
    for (int off = 1; off < 64; off <<= 1) {
      s1 += __shfl_xor(s1, off, 64);
      s2 += __shfl_xor(s2, off, 64);
    }
    if ((t & 63) == 0) { red[t >> 6] = s1; red[4 + (t >> 6)] = s2; }
    __syncthreads();
    if (t == 0) {
      s1 = red[0] + red[1] + red[2] + red[3];
      s2 = red[4] + red[5] + red[6] + red[7];
      const float mu = s1 * (1.0f / 8192.0f);
      const float var = s2 * (1.0f / 8192.0f) - mu * mu;
      const float sc = rsqrtf(var + 1e-5f) * gk[kc] * SFC;
      scsh[0] = sc;
      scsh[1] = bk[kc] * SFC - mu * sc;
    }
    __syncthreads();
  }
  const float sc = scsh[0], sh = scsh[1];

  const float4* row = (const float4*)(Pk + (size_t)kc * 8192 + b * 1024);
  float4 v = row[t];
  float y0 = v.x * sc + sh, y1 = v.y * sc + sh;
  float y2 = v.z * sc + sh, y3 = v.w * sc + sh;
  float m = fmaxf(fmaxf(y0, y1), fmaxf(y2, y3));
#pragma unroll
  for (int off = 32; off; off >>= 1) m = fmaxf(m, __shfl_xor(m, off, 64));
  __shared__ float red2[8];
  const int w = t >> 6, lane = t & 63;
  if (lane == 0) red2[w] = m;
  __syncthreads();
  m = fmaxf(fmaxf(red2[0], red2[1]), fmaxf(red2[2], red2[3]));
  const float e0 = __expf(y0 - m), e1 = __expf(y1 - m);
  const float e2 = __expf(y2 - m), e3 = __expf(y3 - m);
  float su = e0 + e1 + e2 + e3;
#pragma unroll
  for (int off = 32; off; off >>= 1) su += __shfl_xor(su, off, 64);
  if (lane == 0) red2[4 + w] = su;
  __syncthreads();
  const float inv = 1.0f / (red2[4] + red2[5] + red2[6] + red2[7]);
  ushort4 u;
  u.x = bfb(e0 * inv); u.y = bfb(e1 * inv);
  u.z = bfb(e2 * inv); u.w = bfb(e3 * inv);
  ((ushort4*)(KSB + (size_t)(b * 64 + kc) * 1024))[t] = u;
}

// ---------------------------------------------------------------------------
// K3: content context via MFMA: ctx[k][v] = sum_n ks[k][n]*v[v][n] per b.
// KS staged in LDS; V fragments reg-direct from VB2. Grid 8, 4 waves.
// ---------------------------------------------------------------------------
__global__ __launch_bounds__(256) void k_ctxm(
    const ushort_t* __restrict__ KSB, const ushort_t* __restrict__ VB2,
    ushort_t* __restrict__ CTXB)
{
  __shared__ ushort_t KT[2][64 * 72];
  const int b = blockIdx.x, t = threadIdx.x;
  const int w = t >> 6, l = t & 63, ln = l & 31, hi = l >> 5;
  const int a = w & 1, bt = w >> 1;

  auto stageK = [&](int ch, int buf) {
    const int n0 = ch * 64;
#pragma unroll
    for (int it = 0; it < 2; ++it) {
      const int idx = t + it * 256;
      const int row = idx >> 3, seg = idx & 7;
      *(short8*)(&KT[buf][row * 72 + seg * 8]) =
          *(const short8*)(KSB + (size_t)(b * 64 + row) * 1024 + n0 + seg * 8);
    }
  };

  f32x16 acc;
#pragma unroll
  for (int i = 0; i < 16; ++i) acc[i] = 0.f;

  stageK(0, 0);
  for (int ch = 0; ch < 16; ++ch) {
    const int cur = ch & 1;
    __syncthreads();
    if (ch + 1 < 16) stageK(ch + 1, cur ^ 1);
    const ushort_t* ka = &KT[cur][(a * 32 + ln) * 72 + hi * 8];
#pragma unroll
    for (int cc = 0; cc < 4; ++cc) {
      const int i2 = ch * 2 + (cc >> 1), c = cc & 1;
      short8 bf = *(const short8*)(VB2 +
          (((size_t)(b * 32 + i2) * 2 + bt) * 2 + c) * 512 + l * 8);
      acc = __builtin_amdgcn_mfma_f32_32x32x16_bf16(
          *(const short8*)(ka + cc * 16), bf, acc, 0, 0, 0);
    }
  }
#pragma unroll
  for (int r = 0; r < 16; ++r) {
    const int kc = a * 32 + (r & 3) + 8 * (r >> 2) + 4 * hi;
    CTXB[(size_t)b * 4608 + (bt * 32 + ln) * 72 + kc] = bfb(acc[r]);
  }
}

// ---------------------------------------------------------------------------
// K4: positional lambda, block = (b, i1), grid 256, 8 waves (head m, group g).
// Barrier-free main loop; q fragments reg-direct from QB with in-register
// BN scale; rpe/V fragments reg-direct; LDS only for shear + ctx + out.
// ---------------------------------------------------------------------------
extern __shared__ char ldsc[];

__global__ __launch_bounds__(512) void k_pos(
    const ushort_t* __restrict__ QB, const ushort_t* __restrict__ RPEB2,
    const ushort_t* __restrict__ VB2, const float* __restrict__ SCALE,
    const float* __restrict__ SHIFT, const ushort_t* __restrict__ CTXB,
    float* __restrict__ out)
{
  float* out_l = (float*)ldsc;                 // [256][33] f32 = 33792
  ushort_t* SlB = (ushort_t*)(ldsc + 33792);   // 8 waves x [32][40] = 20480
  char* CtxL = ldsc + 54272;                   // 9216 (ctx^T [v][72] bf16)
                                               // total 63488

  const int t = threadIdx.x;
  const int b = blockIdx.x >> 5, i1 = blockIdx.x & 31;
  const int w = t >> 6, l = t & 63, ln = l & 31, hi = l >> 5;
  const int m = w & 3, g = w >> 2;

  // ---- issue ctx staging now; consumed after the post-loop barrier ----
  {
    const char* cs = (const char*)CTXB + (size_t)b * 9216;
    gl16(cs + w * 1024 + l * 16, CtxL + w * 1024 + l * 16);
    if (w == 0) gl16(cs + 8192 + l * 16, CtxL + 8192 + l * 16);
  }

  const ushort_t* rbase = RPEB2 + (size_t)(g * 16 - i1 + 31) * 4096;
  const ushort_t* vbase = VB2 + (size_t)(b * 32 + g * 16) * 2048;

  // prologue prefetch: rpe frags for s=0
  short8 rA[8], rB[8];
#pragma unroll
  for (int f = 0; f < 8; ++f) rA[f] = *(const short8*)(rbase + f * 512 + l * 8);

  // ---- q fragments reg-direct + in-register BN scale ----
  short8 qf[4];
  {
    const ushort_t* qb = QB + (((size_t)(b * 32 + i1) * 4 + m) * 4) * 512 + l * 8;
#pragma unroll
    for (int kc = 0; kc < 4; ++kc) {
      S8 raw; raw.v = *(const short8*)(qb + kc * 512);
      const int chb = m * 64 + kc * 16 + hi * 8;
      F4 s0, s1, h0, h1;
      s0.v = ld4(SCALE + chb); s1.v = ld4(SCALE + chb + 4);
      h0.v = ld4(SHIFT + chb); h1.v = ld4(SHIFT + chb + 4);
      S8 o;
#pragma unroll
      for (int i = 0; i < 8; ++i) {
        const float f = bf2f(raw.u[i]);
        const float scv = (i < 4) ? s0.f[i] : s1.f[i - 4];
        const float shv = (i < 4) ? h0.f[i] : h1.f[i - 4];
        o.u[i] = bfb(f * scv + shv);
      }
      qf[kc] = o.v;
    }
  }

  f32x16 sv0, sv1;
#pragma unroll
  for (int i = 0; i < 16; ++i) { sv0[i] = 0.f; sv1[i] = 0.f; }

  ushort_t* sm = SlB + w * 1280;               // private S tile [32 j1][40]

  auto body = [&](int s, const short8* R) {
    const ushort_t* vp = vbase + (size_t)s * 2048 + l * 8;
    short8 v00 = *(const short8*)(vp);
    short8 v01 = *(const short8*)(vp + 512);
    short8 v10 = *(const short8*)(vp + 1024);
    short8 v11 = *(const short8*)(vp + 1536);
    f32x16 t0, t1;
#pragma unroll
    for (int i = 0; i < 16; ++i) { t0[i] = 0.f; t1[i] = 0.f; }
#pragma unroll
    for (int kc = 0; kc < 4; ++kc) {
      t0 = __builtin_amdgcn_mfma_f32_32x32x16_bf16(qf[kc], R[kc],     t0, 0, 0, 0);
      t1 = __builtin_amdgcn_mfma_f32_32x32x16_bf16(qf[kc], R[4 + kc], t1, 0, 0, 0);
    }
#pragma unroll
    for (int r = 0; r < 16; ++r) {
      const int j1 = (r & 3) + 8 * (r >> 2) + 4 * hi;
      const int j2a = ln + j1 - 31;
      const int j2b = 32 + ln + j1 - 31;
      if ((unsigned)j2a < 32u) sm[j1 * 40 + j2a] = bfb(t0[r]);
      if ((unsigned)j2b < 32u) sm[j1 * 40 + j2b] = bfb(t1[r]);
    }
    const ushort_t* sa = sm + ln * 40 + hi * 8;
    short8 sA0 = *(const short8*)(sa);
    short8 sA1 = *(const short8*)(sa + 16);
    sv0 = __builtin_amdgcn_mfma_f32_32x32x16_bf16(sA0, v00, sv0, 0, 0, 0);
    sv0 = __builtin_amdgcn_mfma_f32_32x32x16_bf16(sA1, v01, sv0, 0, 0, 0);
    sv1 = __builtin_amdgcn_mfma_f32_32x32x16_bf16(sA0, v10, sv1, 0, 0, 0);
    sv1 = __builtin_amdgcn_mfma_f32_32x32x16_bf16(sA1, v11, sv1, 0, 0, 0);
  };

  for (int s = 0; s < 16; s += 2) {
    {
      const ushort_t* rn = rbase + (size_t)(s + 1) * 4096;
#pragma unroll
      for (int f = 0; f < 8; ++f) rB[f] = *(const short8*)(rn + f * 512 + l * 8);
    }
    body(s, rA);
    if (s + 2 < 16) {
      const ushort_t* rn = rbase + (size_t)(s + 2) * 4096;
#pragma unroll
      for (int f = 0; f < 8; ++f) rA[f] = *(const short8*)(rn + f * 512 + l * 8);
    }
    body(s + 1, rB);
  }

  __syncthreads();   // loop done; drains ctx gl16; SlB dead

  if (g == 0) {
    const ushort_t* cb = (const ushort_t*)CtxL;
    const ushort_t* c0 = cb + ln * 72 + hi * 8;
    const ushort_t* c1 = cb + (32 + ln) * 72 + hi * 8;
#pragma unroll
    for (int kc = 0; kc < 4; ++kc) {
      sv0 = __builtin_amdgcn_mfma_f32_32x32x16_bf16(qf[kc], *(const short8*)(c0 + kc * 16), sv0, 0, 0, 0);
      sv1 = __builtin_amdgcn_mfma_f32_32x32x16_bf16(qf[kc], *(const short8*)(c1 + kc * 16), sv1, 0, 0, 0);
    }
  } else {
#pragma unroll
    for (int r = 0; r < 16; ++r) {
      const int j1 = (r & 3) + 8 * (r >> 2) + 4 * hi;
      out_l[(m * 64 + ln) * 33 + j1]      = sv0[r];
      out_l[(m * 64 + 32 + ln) * 33 + j1] = sv1[r];
    }
  }
  __syncthreads();
  if (g == 0) {
#pragma unroll
    for (int r = 0; r < 16; ++r) {
      const int j1 = (r & 3) + 8 * (r >> 2) + 4 * hi;
      out_l[(m * 64 + ln) * 33 + j1]      += sv0[r];
      out_l[(m * 64 + 32 + ln) * 33 + j1] += sv1[r];
    }
  }
  __syncthreads();
  {
    const int ch = t >> 1, jh = (t & 1) * 16;
    float* dst = out + (size_t)b * 262144 + (size_t)ch * 1024 + i1 * 32 + jh;
    const float* srow = out_l + ch * 33 + jh;
#pragma unroll
    for (int gq2 = 0; gq2 < 4; ++gq2)
      st4(dst + gq2 * 4, make_float4(srow[gq2 * 4], srow[gq2 * 4 + 1],
                                     srow[gq2 * 4 + 2], srow[gq2 * 4 + 3]));
  }
}

// ---------------------------------------------------------------------------
extern "C" void kernel_launch(void* const* d_in, const int* in_sizes, int n_in,
                              void* d_out, int out_size, void* d_ws, size_t ws_size,
                              hipStream_t stream) {
  const float* x   = (const float*)d_in[0];
  const float* wq  = (const float*)d_in[1];
  const float* gq  = (const float*)d_in[2];
  const float* bq  = (const float*)d_in[3];
  const float* wk  = (const float*)d_in[4];
  const float* gk  = (const float*)d_in[5];
  const float* bk  = (const float*)d_in[6];
  const float* wv  = (const float*)d_in[7];
  const float* rpe = (const float*)d_in[8];
  float* out = (float*)d_out;
  char* W = (char*)d_ws;

  float* Pk       = (float*)W;                       //  2,097,152 B
  ushort_t* QB    = (ushort_t*)(W + 2097152);        //  4,194,304
  ushort_t* KSB   = (ushort_t*)(W + 6291456);        //  1,048,576
  float* PSUM     = (float*)(W + 7340032);           //    163,840
  float* PSQ      = (float*)(W + 7503872);           //    163,840
  float* SCALE    = (float*)(W + 7667712);           //      2,048
  float* SHIFT    = (float*)(W + 7669760);           //      2,048
  ushort_t* CTXB  = (ushort_t*)(W + 7671808);        //     73,728
  ushort_t* RPEB2 = (ushort_t*)(W + 7745536);        //    516,096
  ushort_t* VB2   = (ushort_t*)(W + 8261632);        //  1,048,576
  ushort_t* WB    = (ushort_t*)(W + 9310208);        //    196,608
  ushort_t* XBT   = (ushort_t*)(W + 9506816);        //  4,194,304

  k_prep<<<1135, 256, 0, stream>>>(rpe, wq, wk, wv, x, RPEB2, WB, XBT);
  k_projm<<<dim3(6, 64), 256, 0, stream>>>(WB, XBT, Pk, QB, VB2, PSUM, PSQ);
  k_softmax<<<768, 256, 0, stream>>>(Pk, PSUM, PSQ, gq, bq, gk, bk, SCALE, SHIFT, KSB);
  k_ctxm<<<8, 256, 0, stream>>>(KSB, VB2, CTXB);

  hipFuncSetAttribute((const void*)k_pos,
                      hipFuncAttributeMaxDynamicSharedMemorySize, 63488);
  k_pos<<<256, 512, 63488, stream>>>(QB, RPEB2, VB2, SCALE, SHIFT, CTXB, out);
}